// Round 3
// baseline (451.328 us; speedup 1.0000x reference)
//
#include <hip/hip_runtime.h>
#include <hip/hip_bf16.h>

#define NHEAD 12
#define TSEQ 2048
#define CEMB 768
#define DHEAD 64
#define NBATCH 4

typedef __attribute__((ext_vector_type(8))) short bf16x8;
typedef __attribute__((ext_vector_type(4))) float f32x4;

__device__ __forceinline__ ushort f2bf(float f) {
  union { float f; unsigned u; } v; v.f = f;
  unsigned u = v.u;
  u += 0x7FFFu + ((u >> 16) & 1u);   // RNE to bf16
  return (ushort)(u >> 16);
}

// wave-local LDS ordering (P buffer is wave-private; no block barrier needed)
__device__ __forceinline__ void lds_fence() {
  asm volatile("s_waitcnt lgkmcnt(0)" ::: "memory");
  __builtin_amdgcn_sched_barrier(0);   // rule 18: pin ops after the waitcnt
}

// ---------- fp32 [R][C] -> bf16 [C][R] (weight pre-transpose) ----------
__global__ void transpose_w(const float* __restrict__ src, ushort* __restrict__ dst,
                            int R, int C) {
  __shared__ float tile[32][33];
  int c0 = blockIdx.x * 32, r0 = blockIdx.y * 32;
  int tx = threadIdx.x, ty = threadIdx.y;  // block (32,8)
#pragma unroll
  for (int j = 0; j < 4; ++j)
    tile[ty + j * 8][tx] = src[(size_t)(r0 + ty + j * 8) * C + c0 + tx];
  __syncthreads();
#pragma unroll
  for (int j = 0; j < 4; ++j)
    dst[(size_t)(c0 + ty + j * 8) * R + r0 + tx] = f2bf(tile[tx][ty + j * 8]);
}

// ---------- bf16 v [BH][T][D] -> vT [BH][D][T] ----------
__global__ void transpose_v(const ushort* __restrict__ src, ushort* __restrict__ dst) {
  __shared__ ushort tile[32][33];
  int bh = blockIdx.z;
  int t0 = blockIdx.x * 32, d0 = blockIdx.y * 32;
  int tx = threadIdx.x, ty = threadIdx.y;  // block (32,8)
  const ushort* s = src + (size_t)bh * TSEQ * DHEAD;
  ushort* o = dst + (size_t)bh * TSEQ * DHEAD;
#pragma unroll
  for (int j = 0; j < 4; ++j)
    tile[ty + j * 8][tx] = s[(t0 + ty + j * 8) * DHEAD + d0 + tx];
  __syncthreads();
#pragma unroll
  for (int j = 0; j < 4; ++j)
    o[(size_t)(d0 + ty + j * 8) * TSEQ + t0 + tx] = tile[tx][ty + j * 8];
}

// ---------- bf16 MFMA GEMM: C[M][N] = A(fp32,[M][K]) * BT(bf16,[N][K])^T + bias ----------
// EPI=0: fp32 out [M][N].  EPI=1: scatter qkv -> q/k/v bf16 [B,H,T,D], q pre-scaled by 1/8.
template<int EPI>
__global__ __launch_bounds__(256)
void gemm_bf16(const float* __restrict__ A, const ushort* __restrict__ BT,
               const float* __restrict__ bias, float* __restrict__ outF,
               ushort* __restrict__ qd, ushort* __restrict__ kd, ushort* __restrict__ vd,
               int M, int N, int K)
{
  __shared__ ushort As[128][40];   // BK=32 + 8 pad
  __shared__ ushort Bs[128][40];
  const int t = threadIdx.x;
  const int lane = t & 63, wv = t >> 6;
  const int cc = lane & 15, gg = lane >> 4;
  const int m0 = blockIdx.y * 128, n0 = blockIdx.x * 128;
  const int wm = (wv >> 1) * 64, wn = (wv & 1) * 64;
  const int srow = t >> 1, scol = (t & 1) * 16;

  f32x4 acc[4][4];
#pragma unroll
  for (int i = 0; i < 4; ++i)
#pragma unroll
    for (int j = 0; j < 4; ++j) acc[i][j] = (f32x4){0.f, 0.f, 0.f, 0.f};

  const float*  ap = A  + (size_t)(m0 + srow) * K + scol;
  const ushort* bp = BT + (size_t)(n0 + srow) * K + scol;

  for (int kt = 0; kt < K; kt += 32) {
    float4 a0 = *(const float4*)(ap + kt);
    float4 a1 = *(const float4*)(ap + kt + 4);
    float4 a2 = *(const float4*)(ap + kt + 8);
    float4 a3 = *(const float4*)(ap + kt + 12);
    bf16x8 b0 = *(const bf16x8*)(bp + kt);
    bf16x8 b1 = *(const bf16x8*)(bp + kt + 8);
    __syncthreads();   // previous iteration's LDS reads done before overwrite
    bf16x8 w0, w1;
    w0[0] = (short)f2bf(a0.x); w0[1] = (short)f2bf(a0.y);
    w0[2] = (short)f2bf(a0.z); w0[3] = (short)f2bf(a0.w);
    w0[4] = (short)f2bf(a1.x); w0[5] = (short)f2bf(a1.y);
    w0[6] = (short)f2bf(a1.z); w0[7] = (short)f2bf(a1.w);
    w1[0] = (short)f2bf(a2.x); w1[1] = (short)f2bf(a2.y);
    w1[2] = (short)f2bf(a2.z); w1[3] = (short)f2bf(a2.w);
    w1[4] = (short)f2bf(a3.x); w1[5] = (short)f2bf(a3.y);
    w1[6] = (short)f2bf(a3.z); w1[7] = (short)f2bf(a3.w);
    *(bf16x8*)&As[srow][scol]     = w0;
    *(bf16x8*)&As[srow][scol + 8] = w1;
    *(bf16x8*)&Bs[srow][scol]     = b0;
    *(bf16x8*)&Bs[srow][scol + 8] = b1;
    __syncthreads();
    bf16x8 fa[4], fb[4];
#pragma unroll
    for (int i = 0; i < 4; ++i) fa[i] = *(const bf16x8*)&As[wm + i * 16 + cc][8 * gg];
#pragma unroll
    for (int j = 0; j < 4; ++j) fb[j] = *(const bf16x8*)&Bs[wn + j * 16 + cc][8 * gg];
#pragma unroll
    for (int i = 0; i < 4; ++i)
#pragma unroll
      for (int j = 0; j < 4; ++j)
        acc[i][j] = __builtin_amdgcn_mfma_f32_16x16x32_bf16(fa[i], fb[j], acc[i][j], 0, 0, 0);
  }

#pragma unroll
  for (int i = 0; i < 4; ++i) {
#pragma unroll
    for (int j = 0; j < 4; ++j) {
      int gm0 = m0 + wm + i * 16 + gg * 4;
      int gn  = n0 + wn + j * 16 + cc;
      float bv = bias[gn];
      if (EPI == 0) {
#pragma unroll
        for (int e = 0; e < 4; ++e)
          outF[(size_t)(gm0 + e) * N + gn] = acc[i][j][e] + bv;
      } else {
        int which = gn / CEMB;
        int r = gn - which * CEMB;
        int hh = r >> 6, dd = r & 63;
        ushort* dst = which == 0 ? qd : (which == 1 ? kd : vd);
        float sc = (which == 0) ? 0.125f : 1.0f;   // fold 1/sqrt(D) into Q (exact)
#pragma unroll
        for (int e = 0; e < 4; ++e) {
          int gm = gm0 + e;
          int tt = gm & (TSEQ - 1), bb = gm >> 11;
          dst[(size_t)((bb * NHEAD + hh) * TSEQ + tt) * DHEAD + dd] = f2bf((acc[i][j][e] + bv) * sc);
        }
      }
    }
  }
}

// ---------- flash attention: q,k [BH][T][D] bf16, vT [BH][D][T] bf16 -> ybuf fp32 [B][T][C] ----------
// One wave per 16-row q-chunk (6144 waves total = 24/CU nominal). All 4 waves in a
// block share the same kt bound; heaviest blocks dispatched first (reversed index).
__global__ __launch_bounds__(256)
void attn_fwd(const ushort* __restrict__ qg, const ushort* __restrict__ kg,
              const ushort* __restrict__ vTg, float* __restrict__ ybuf)
{
  __shared__ ushort Pl[4][16][80];   // per-wave P tile [16 q][64 key], stride 80
  const int t = threadIdx.x, lane = t & 63, w = t >> 6;
  const int cc = lane & 15, gg = lane >> 4;
  const int qt = gridDim.x - 1 - blockIdx.x;   // heavy tiles first
  const int bh = blockIdx.y;
  const int b = bh / NHEAD, h = bh - b * NHEAD;
  const int qrow0 = qt * 64 + w * 16;

  const ushort* Qp = qg + ((size_t)bh * TSEQ + qrow0) * DHEAD;
  bf16x8 fq0 = *(const bf16x8*)(Qp + cc * DHEAD + 8 * gg);
  bf16x8 fq1 = *(const bf16x8*)(Qp + cc * DHEAD + 32 + 8 * gg);

  f32x4 o[4];
  float mrow[4], lrow[4];
#pragma unroll
  for (int i = 0; i < 4; ++i) { o[i] = (f32x4){0.f,0.f,0.f,0.f}; mrow[i] = -1e30f; lrow[i] = 0.f; }

  for (int kt = 0; kt <= qt; ++kt) {
    const ushort* Kp = kg + ((size_t)bh * TSEQ + kt * 64) * DHEAD;
    f32x4 s[4];
#pragma unroll
    for (int ct = 0; ct < 4; ++ct) s[ct] = (f32x4){0.f,0.f,0.f,0.f};
#pragma unroll
    for (int ct = 0; ct < 4; ++ct) {
      bf16x8 fk0 = *(const bf16x8*)(Kp + (ct * 16 + cc) * DHEAD + 8 * gg);
      bf16x8 fk1 = *(const bf16x8*)(Kp + (ct * 16 + cc) * DHEAD + 32 + 8 * gg);
      s[ct] = __builtin_amdgcn_mfma_f32_16x16x32_bf16(fq0, fk0, s[ct], 0, 0, 0);
      s[ct] = __builtin_amdgcn_mfma_f32_16x16x32_bf16(fq1, fk1, s[ct], 0, 0, 0);
    }
    if (kt == qt) {   // diagonal tile: causal mask (Q already pre-scaled by 1/8)
#pragma unroll
      for (int ct = 0; ct < 4; ++ct)
#pragma unroll
        for (int e = 0; e < 4; ++e) {
          int key = ct * 16 + cc;
          int row = w * 16 + gg * 4 + e;
          if (key > row) s[ct][e] = -1e30f;
        }
    }
    float mn[4], al[4], ps[4];
#pragma unroll
    for (int e = 0; e < 4; ++e) {
      float ml = fmaxf(fmaxf(s[0][e], s[1][e]), fmaxf(s[2][e], s[3][e]));
#pragma unroll
      for (int off = 1; off < 16; off <<= 1) ml = fmaxf(ml, __shfl_xor(ml, off, 64));
      mn[e] = fmaxf(mrow[e], ml);
      al[e] = __expf(mrow[e] - mn[e]);
      mrow[e] = mn[e];
      ps[e] = 0.f;
    }
#pragma unroll
    for (int ct = 0; ct < 4; ++ct)
#pragma unroll
      for (int e = 0; e < 4; ++e) { float pp = __expf(s[ct][e] - mn[e]); s[ct][e] = pp; ps[e] += pp; }
#pragma unroll
    for (int e = 0; e < 4; ++e) {
#pragma unroll
      for (int off = 1; off < 16; off <<= 1) ps[e] += __shfl_xor(ps[e], off, 64);
      lrow[e] = lrow[e] * al[e] + ps[e];
    }
#pragma unroll
    for (int dt = 0; dt < 4; ++dt)
#pragma unroll
      for (int e = 0; e < 4; ++e) o[dt][e] *= al[e];
#pragma unroll
    for (int ct = 0; ct < 4; ++ct)
#pragma unroll
      for (int e = 0; e < 4; ++e) Pl[w][gg * 4 + e][ct * 16 + cc] = f2bf(s[ct][e]);
    lds_fence();   // wave-local: P writes complete before fragment reads
    const ushort* Vp = vTg + (size_t)bh * TSEQ * DHEAD + kt * 64;
#pragma unroll
    for (int kc = 0; kc < 2; ++kc) {
      bf16x8 pa = *(const bf16x8*)&Pl[w][cc][kc * 32 + 8 * gg];
#pragma unroll
      for (int dt = 0; dt < 4; ++dt) {
        bf16x8 fv = *(const bf16x8*)(Vp + (size_t)(dt * 16 + cc) * TSEQ + kc * 32 + 8 * gg);
        o[dt] = __builtin_amdgcn_mfma_f32_16x16x32_bf16(pa, fv, o[dt], 0, 0, 0);
      }
    }
  }
#pragma unroll
  for (int dt = 0; dt < 4; ++dt)
#pragma unroll
    for (int e = 0; e < 4; ++e) {
      int row = qrow0 + gg * 4 + e;
      int col = h * DHEAD + dt * 16 + cc;
      ybuf[((size_t)b * TSEQ + row) * CEMB + col] = o[dt][e] / lrow[e];
    }
}

extern "C" void kernel_launch(void* const* d_in, const int* in_sizes, int n_in,
                              void* d_out, int out_size, void* d_ws, size_t ws_size,
                              hipStream_t stream)
{
  (void)in_sizes; (void)n_in; (void)out_size; (void)ws_size;
  const float* x  = (const float*)d_in[0];
  const float* Wa = (const float*)d_in[1];
  const float* ba = (const float*)d_in[2];
  const float* Wo = (const float*)d_in[3];
  const float* bo = (const float*)d_in[4];
  float* out = (float*)d_out;

  char* p = (char*)d_ws;
  ushort* WaT  = (ushort*)p; p += (size_t)3 * CEMB * CEMB * 2;              // [2304][768] bf16
  ushort* WoT  = (ushort*)p; p += (size_t)CEMB * CEMB * 2;                  // [768][768] bf16
  ushort* qb   = (ushort*)p; p += (size_t)NBATCH * NHEAD * TSEQ * DHEAD * 2; // [B,H,T,D]
  ushort* kb   = (ushort*)p; p += (size_t)NBATCH * NHEAD * TSEQ * DHEAD * 2;
  ushort* vtmp = (ushort*)p; p += (size_t)NBATCH * NHEAD * TSEQ * DHEAD * 2;
  ushort* vT   = (ushort*)p; p += (size_t)NBATCH * NHEAD * TSEQ * DHEAD * 2; // [B,H,D,T]
  float*  yb   = (float*)p;  p += (size_t)NBATCH * TSEQ * CEMB * 4;          // fp32 [B,T,C]

  dim3 tb(32, 8);
  transpose_w<<<dim3(3 * CEMB / 32, CEMB / 32), tb, 0, stream>>>(Wa, WaT, CEMB, 3 * CEMB);
  transpose_w<<<dim3(CEMB / 32, CEMB / 32), tb, 0, stream>>>(Wo, WoT, CEMB, CEMB);
  gemm_bf16<1><<<dim3(3 * CEMB / 128, NBATCH * TSEQ / 128), 256, 0, stream>>>(
      x, WaT, ba, nullptr, qb, kb, vtmp, NBATCH * TSEQ, 3 * CEMB, CEMB);
  transpose_v<<<dim3(TSEQ / 32, DHEAD / 32, NBATCH * NHEAD), tb, 0, stream>>>(vtmp, vT);
  attn_fwd<<<dim3(TSEQ / 64, NBATCH * NHEAD), 256, 0, stream>>>(qb, kb, vT, yb);
  gemm_bf16<0><<<dim3(CEMB / 128, NBATCH * TSEQ / 128), 256, 0, stream>>>(
      yb, WoT, bo, out, nullptr, nullptr, nullptr, NBATCH * TSEQ, CEMB, CEMB);
}

// Round 4
// 292.232 us; speedup vs baseline: 1.5444x; 1.5444x over previous
//
#include <hip/hip_runtime.h>
#include <hip/hip_bf16.h>

#define NHEAD 12
#define TSEQ 2048
#define CEMB 768
#define DHEAD 64
#define NBATCH 4

typedef __attribute__((ext_vector_type(8))) short bf16x8;
typedef __attribute__((ext_vector_type(4))) float f32x4;

__device__ __forceinline__ ushort f2bf(float f) {
  union { float f; unsigned u; } v; v.f = f;
  unsigned u = v.u;
  u += 0x7FFFu + ((u >> 16) & 1u);   // RNE to bf16
  return (ushort)(u >> 16);
}

// wave-local LDS ordering (P buffer is wave-private; no block barrier needed)
__device__ __forceinline__ void lds_fence() {
  asm volatile("s_waitcnt lgkmcnt(0)" ::: "memory");
  __builtin_amdgcn_sched_barrier(0);   // rule 18: pin ops after the waitcnt
}

// ---------- fp32 [R][C] -> bf16 [C][R] (weight pre-transpose) ----------
__global__ void transpose_w(const float* __restrict__ src, ushort* __restrict__ dst,
                            int R, int C) {
  __shared__ float tile[32][33];
  int c0 = blockIdx.x * 32, r0 = blockIdx.y * 32;
  int tx = threadIdx.x, ty = threadIdx.y;  // block (32,8)
#pragma unroll
  for (int j = 0; j < 4; ++j)
    tile[ty + j * 8][tx] = src[(size_t)(r0 + ty + j * 8) * C + c0 + tx];
  __syncthreads();
#pragma unroll
  for (int j = 0; j < 4; ++j)
    dst[(size_t)(c0 + ty + j * 8) * R + r0 + tx] = f2bf(tile[tx][ty + j * 8]);
}

// ---------- bf16 v [BH][T][D] -> vT [BH][D][T] ----------
__global__ void transpose_v(const ushort* __restrict__ src, ushort* __restrict__ dst) {
  __shared__ ushort tile[32][33];
  int bh = blockIdx.z;
  int t0 = blockIdx.x * 32, d0 = blockIdx.y * 32;
  int tx = threadIdx.x, ty = threadIdx.y;  // block (32,8)
  const ushort* s = src + (size_t)bh * TSEQ * DHEAD;
  ushort* o = dst + (size_t)bh * TSEQ * DHEAD;
#pragma unroll
  for (int j = 0; j < 4; ++j)
    tile[ty + j * 8][tx] = s[(t0 + ty + j * 8) * DHEAD + d0 + tx];
  __syncthreads();
#pragma unroll
  for (int j = 0; j < 4; ++j)
    o[(size_t)(d0 + ty + j * 8) * TSEQ + t0 + tx] = tile[tx][ty + j * 8];
}

// ---------- bf16 MFMA GEMM: C[M][N] = A(fp32,[M][K]) * BT(bf16,[N][K])^T + bias ----------
// EPI=0: fp32 out [M][N].  EPI=1: scatter qkv -> q/k/v bf16 [B,H,T,D], q pre-scaled by 1/8.
template<int EPI>
__global__ __launch_bounds__(256)
void gemm_bf16(const float* __restrict__ A, const ushort* __restrict__ BT,
               const float* __restrict__ bias, float* __restrict__ outF,
               ushort* __restrict__ qd, ushort* __restrict__ kd, ushort* __restrict__ vd,
               int M, int N, int K)
{
  __shared__ ushort As[128][40];   // BK=32 + 8 pad
  __shared__ ushort Bs[128][40];
  const int t = threadIdx.x;
  const int lane = t & 63, wv = t >> 6;
  const int cc = lane & 15, gg = lane >> 4;
  const int m0 = blockIdx.y * 128, n0 = blockIdx.x * 128;
  const int wm = (wv >> 1) * 64, wn = (wv & 1) * 64;
  const int srow = t >> 1, scol = (t & 1) * 16;

  f32x4 acc[4][4];
#pragma unroll
  for (int i = 0; i < 4; ++i)
#pragma unroll
    for (int j = 0; j < 4; ++j) acc[i][j] = (f32x4){0.f, 0.f, 0.f, 0.f};

  const float*  ap = A  + (size_t)(m0 + srow) * K + scol;
  const ushort* bp = BT + (size_t)(n0 + srow) * K + scol;

  for (int kt = 0; kt < K; kt += 32) {
    float4 a0 = *(const float4*)(ap + kt);
    float4 a1 = *(const float4*)(ap + kt + 4);
    float4 a2 = *(const float4*)(ap + kt + 8);
    float4 a3 = *(const float4*)(ap + kt + 12);
    bf16x8 b0 = *(const bf16x8*)(bp + kt);
    bf16x8 b1 = *(const bf16x8*)(bp + kt + 8);
    __syncthreads();   // previous iteration's LDS reads done before overwrite
    bf16x8 w0, w1;
    w0[0] = (short)f2bf(a0.x); w0[1] = (short)f2bf(a0.y);
    w0[2] = (short)f2bf(a0.z); w0[3] = (short)f2bf(a0.w);
    w0[4] = (short)f2bf(a1.x); w0[5] = (short)f2bf(a1.y);
    w0[6] = (short)f2bf(a1.z); w0[7] = (short)f2bf(a1.w);
    w1[0] = (short)f2bf(a2.x); w1[1] = (short)f2bf(a2.y);
    w1[2] = (short)f2bf(a2.z); w1[3] = (short)f2bf(a2.w);
    w1[4] = (short)f2bf(a3.x); w1[5] = (short)f2bf(a3.y);
    w1[6] = (short)f2bf(a3.z); w1[7] = (short)f2bf(a3.w);
    *(bf16x8*)&As[srow][scol]     = w0;
    *(bf16x8*)&As[srow][scol + 8] = w1;
    *(bf16x8*)&Bs[srow][scol]     = b0;
    *(bf16x8*)&Bs[srow][scol + 8] = b1;
    __syncthreads();
    bf16x8 fa[4], fb[4];
#pragma unroll
    for (int i = 0; i < 4; ++i) fa[i] = *(const bf16x8*)&As[wm + i * 16 + cc][8 * gg];
#pragma unroll
    for (int j = 0; j < 4; ++j) fb[j] = *(const bf16x8*)&Bs[wn + j * 16 + cc][8 * gg];
#pragma unroll
    for (int i = 0; i < 4; ++i)
#pragma unroll
      for (int j = 0; j < 4; ++j)
        acc[i][j] = __builtin_amdgcn_mfma_f32_16x16x32_bf16(fa[i], fb[j], acc[i][j], 0, 0, 0);
  }

#pragma unroll
  for (int i = 0; i < 4; ++i) {
#pragma unroll
    for (int j = 0; j < 4; ++j) {
      int gm0 = m0 + wm + i * 16 + gg * 4;
      int gn  = n0 + wn + j * 16 + cc;
      float bv = bias[gn];
      if (EPI == 0) {
#pragma unroll
        for (int e = 0; e < 4; ++e)
          outF[(size_t)(gm0 + e) * N + gn] = acc[i][j][e] + bv;
      } else {
        int which = gn / CEMB;
        int r = gn - which * CEMB;
        int hh = r >> 6, dd = r & 63;
        ushort* dst = which == 0 ? qd : (which == 1 ? kd : vd);
        float sc = (which == 0) ? 0.125f : 1.0f;   // fold 1/sqrt(D) into Q (exact)
#pragma unroll
        for (int e = 0; e < 4; ++e) {
          int gm = gm0 + e;
          int tt = gm & (TSEQ - 1), bb = gm >> 11;
          dst[(size_t)((bb * NHEAD + hh) * TSEQ + tt) * DHEAD + dd] = f2bf((acc[i][j][e] + bv) * sc);
        }
      }
    }
  }
}

// ---------- flash attention (swapped-operand): q,k [BH][T][D], vT [BH][D][T] -> ybuf fp32 ----------
// Block bx handles q-tiles bx and NT-1-bx (exactly NT+1 key-tiles per wave: balanced).
// S^T = mfma(K,Q): lane holds 16 scores of ONE q-row -> in-lane reductions + 2 shfl.
// PV as O^T = mfma(V^T, P): V^T frags identical to row-major vT loads; P via 4x ds_write_b64.
__global__ __launch_bounds__(256)
void attn_fwd(const ushort* __restrict__ qg, const ushort* __restrict__ kg,
              const ushort* __restrict__ vTg, float* __restrict__ ybuf)
{
  __shared__ ushort Pl[4][16][80];   // per-wave P^T tile: [q-row (cc)][64 keys], stride 80
  const int t = threadIdx.x, lane = t & 63, w = t >> 6;
  const int cc = lane & 15, gg = lane >> 4;
  const int NT = TSEQ / 64;
  const int bx = blockIdx.x, bh = blockIdx.y;
  const int b = bh / NHEAD, h = bh - b * NHEAD;

  for (int pass = 0; pass < 2; ++pass) {
    const int qt = pass ? (NT - 1 - bx) : bx;
    const int qrow0 = qt * 64 + w * 16;

    const ushort* Qp = qg + ((size_t)bh * TSEQ + qrow0) * DHEAD;
    // Q is the b-operand: lane cc = q-row (qrow0 + cc)
    bf16x8 fq0 = *(const bf16x8*)(Qp + cc * DHEAD + 8 * gg);
    bf16x8 fq1 = *(const bf16x8*)(Qp + cc * DHEAD + 32 + 8 * gg);

    f32x4 o[4];   // O^T: o[dt][e] = O^T[d = dt*16 + gg*4 + e, q = cc]
#pragma unroll
    for (int i = 0; i < 4; ++i) o[i] = (f32x4){0.f, 0.f, 0.f, 0.f};
    float m = -1e30f, l = 0.f;   // per-lane scalars for q-row cc (replicated over gg)

    for (int kt = 0; kt <= qt; ++kt) {
      const ushort* Kp = kg + ((size_t)bh * TSEQ + kt * 64) * DHEAD;
      f32x4 st[4];   // st[ct][e] = S^T[key = 16ct + 4gg + e, q = cc]
#pragma unroll
      for (int ct = 0; ct < 4; ++ct) st[ct] = (f32x4){0.f, 0.f, 0.f, 0.f};
#pragma unroll
      for (int ct = 0; ct < 4; ++ct) {
        bf16x8 fk0 = *(const bf16x8*)(Kp + (ct * 16 + cc) * DHEAD + 8 * gg);
        bf16x8 fk1 = *(const bf16x8*)(Kp + (ct * 16 + cc) * DHEAD + 32 + 8 * gg);
        st[ct] = __builtin_amdgcn_mfma_f32_16x16x32_bf16(fk0, fq0, st[ct], 0, 0, 0);
        st[ct] = __builtin_amdgcn_mfma_f32_16x16x32_bf16(fk1, fq1, st[ct], 0, 0, 0);
      }
      // early-issue this tile's V^T fragment loads; latency hides under softmax
      const ushort* Vp = vTg + (size_t)bh * TSEQ * DHEAD + kt * 64;
      bf16x8 fv[4][2];
#pragma unroll
      for (int dt = 0; dt < 4; ++dt)
#pragma unroll
        for (int kc = 0; kc < 2; ++kc)
          fv[dt][kc] = *(const bf16x8*)(Vp + (size_t)(dt * 16 + cc) * TSEQ + kc * 32 + 8 * gg);

      if (kt == qt) {   // causal mask on the diagonal tile: key > q  (Q pre-scaled by 1/8)
#pragma unroll
        for (int ct = 0; ct < 4; ++ct)
#pragma unroll
          for (int e = 0; e < 4; ++e)
            if (ct * 16 + gg * 4 + e > w * 16 + cc) st[ct][e] = -1e30f;
      }
      // row max: 15 in-lane + 2-shfl butterfly over the 4 gg replicas
      float ml = st[0][0];
#pragma unroll
      for (int ct = 0; ct < 4; ++ct)
#pragma unroll
        for (int e = 0; e < 4; ++e) ml = fmaxf(ml, st[ct][e]);
      ml = fmaxf(ml, __shfl_xor(ml, 16, 64));
      ml = fmaxf(ml, __shfl_xor(ml, 32, 64));
      float mn = fmaxf(m, ml);
      float al = __expf(m - mn);
      float ps = 0.f;
#pragma unroll
      for (int ct = 0; ct < 4; ++ct)
#pragma unroll
        for (int e = 0; e < 4; ++e) { float pp = __expf(st[ct][e] - mn); st[ct][e] = pp; ps += pp; }
      // pack 4 consecutive keys/ct and write 8B each; sum-reduce overlaps write latency
#pragma unroll
      for (int ct = 0; ct < 4; ++ct) {
        uint2 pw;
        pw.x = (unsigned)f2bf(st[ct][0]) | ((unsigned)f2bf(st[ct][1]) << 16);
        pw.y = (unsigned)f2bf(st[ct][2]) | ((unsigned)f2bf(st[ct][3]) << 16);
        *(uint2*)&Pl[w][cc][ct * 16 + gg * 4] = pw;
      }
      ps += __shfl_xor(ps, 16, 64);
      ps += __shfl_xor(ps, 32, 64);
      l = l * al + ps;
      m = mn;
#pragma unroll
      for (int dt = 0; dt < 4; ++dt)
#pragma unroll
        for (int e = 0; e < 4; ++e) o[dt][e] *= al;
      lds_fence();   // wave-local: P writes complete before fragment reads
#pragma unroll
      for (int kc = 0; kc < 2; ++kc) {
        bf16x8 pb = *(const bf16x8*)&Pl[w][cc][kc * 32 + 8 * gg];
#pragma unroll
        for (int dt = 0; dt < 4; ++dt)
          o[dt] = __builtin_amdgcn_mfma_f32_16x16x32_bf16(fv[dt][kc], pb, o[dt], 0, 0, 0);
      }
    }
    float inv = 1.0f / l;
#pragma unroll
    for (int dt = 0; dt < 4; ++dt)
#pragma unroll
      for (int e = 0; e < 4; ++e) {
        int row = qrow0 + cc;
        int col = h * DHEAD + dt * 16 + gg * 4 + e;
        ybuf[((size_t)b * TSEQ + row) * CEMB + col] = o[dt][e] * inv;
      }
  }
}

extern "C" void kernel_launch(void* const* d_in, const int* in_sizes, int n_in,
                              void* d_out, int out_size, void* d_ws, size_t ws_size,
                              hipStream_t stream)
{
  (void)in_sizes; (void)n_in; (void)out_size; (void)ws_size;
  const float* x  = (const float*)d_in[0];
  const float* Wa = (const float*)d_in[1];
  const float* ba = (const float*)d_in[2];
  const float* Wo = (const float*)d_in[3];
  const float* bo = (const float*)d_in[4];
  float* out = (float*)d_out;

  char* p = (char*)d_ws;
  ushort* WaT  = (ushort*)p; p += (size_t)3 * CEMB * CEMB * 2;              // [2304][768] bf16
  ushort* WoT  = (ushort*)p; p += (size_t)CEMB * CEMB * 2;                  // [768][768] bf16
  ushort* qb   = (ushort*)p; p += (size_t)NBATCH * NHEAD * TSEQ * DHEAD * 2; // [B,H,T,D]
  ushort* kb   = (ushort*)p; p += (size_t)NBATCH * NHEAD * TSEQ * DHEAD * 2;
  ushort* vtmp = (ushort*)p; p += (size_t)NBATCH * NHEAD * TSEQ * DHEAD * 2;
  ushort* vT   = (ushort*)p; p += (size_t)NBATCH * NHEAD * TSEQ * DHEAD * 2; // [B,H,D,T]
  float*  yb   = (float*)p;  p += (size_t)NBATCH * TSEQ * CEMB * 4;          // fp32 [B,T,C]

  dim3 tb(32, 8);
  transpose_w<<<dim3(3 * CEMB / 32, CEMB / 32), tb, 0, stream>>>(Wa, WaT, CEMB, 3 * CEMB);
  transpose_w<<<dim3(CEMB / 32, CEMB / 32), tb, 0, stream>>>(Wo, WoT, CEMB, CEMB);
  gemm_bf16<1><<<dim3(3 * CEMB / 128, NBATCH * TSEQ / 128), 256, 0, stream>>>(
      x, WaT, ba, nullptr, qb, kb, vtmp, NBATCH * TSEQ, 3 * CEMB, CEMB);
  transpose_v<<<dim3(TSEQ / 32, DHEAD / 32, NBATCH * NHEAD), tb, 0, stream>>>(vtmp, vT);
  attn_fwd<<<dim3(TSEQ / 128, NBATCH * NHEAD), 256, 0, stream>>>(qb, kb, vT, yb);
  gemm_bf16<0><<<dim3(CEMB / 128, NBATCH * TSEQ / 128), 256, 0, stream>>>(
      yb, WoT, bo, out, nullptr, nullptr, nullptr, NBATCH * TSEQ, CEMB, CEMB);
}

// Round 5
// 183.341 us; speedup vs baseline: 2.4617x; 1.5939x over previous
//
#include <hip/hip_runtime.h>
#include <hip/hip_bf16.h>

#define NHEAD 12
#define TSEQ 2048
#define CEMB 768
#define DHEAD 64
#define NBATCH 4

typedef __attribute__((ext_vector_type(8))) short bf16x8;
typedef __attribute__((ext_vector_type(4))) float f32x4;

__device__ __forceinline__ ushort f2bf(float f) {
  union { float f; unsigned u; } v; v.f = f;
  unsigned u = v.u;
  u += 0x7FFFu + ((u >> 16) & 1u);   // RNE to bf16
  return (ushort)(u >> 16);
}

// wave-local LDS ordering (P buffer is wave-private; no block barrier needed)
__device__ __forceinline__ void lds_fence() {
  asm volatile("s_waitcnt lgkmcnt(0)" ::: "memory");
  __builtin_amdgcn_sched_barrier(0);   // rule 18: pin ops after the waitcnt
}

// ---------- fp32 [R][C] -> bf16 [C][R] (weight pre-transpose) ----------
__global__ void transpose_w(const float* __restrict__ src, ushort* __restrict__ dst,
                            int R, int C) {
  __shared__ float tile[32][33];
  int c0 = blockIdx.x * 32, r0 = blockIdx.y * 32;
  int tx = threadIdx.x, ty = threadIdx.y;  // block (32,8)
#pragma unroll
  for (int j = 0; j < 4; ++j)
    tile[ty + j * 8][tx] = src[(size_t)(r0 + ty + j * 8) * C + c0 + tx];
  __syncthreads();
#pragma unroll
  for (int j = 0; j < 4; ++j)
    dst[(size_t)(c0 + ty + j * 8) * R + r0 + tx] = f2bf(tile[tx][ty + j * 8]);
}

// ---------- bf16 v [BH][T][D] -> vT [BH][D][T] ----------
__global__ void transpose_v(const ushort* __restrict__ src, ushort* __restrict__ dst) {
  __shared__ ushort tile[32][33];
  int bh = blockIdx.z;
  int t0 = blockIdx.x * 32, d0 = blockIdx.y * 32;
  int tx = threadIdx.x, ty = threadIdx.y;  // block (32,8)
  const ushort* s = src + (size_t)bh * TSEQ * DHEAD;
  ushort* o = dst + (size_t)bh * TSEQ * DHEAD;
#pragma unroll
  for (int j = 0; j < 4; ++j)
    tile[ty + j * 8][tx] = s[(t0 + ty + j * 8) * DHEAD + d0 + tx];
  __syncthreads();
#pragma unroll
  for (int j = 0; j < 4; ++j)
    o[(size_t)(d0 + ty + j * 8) * TSEQ + t0 + tx] = tile[tx][ty + j * 8];
}

// ---------- bf16 MFMA GEMM: C[M][N] = A(fp32,[M][K]) * BT(bf16,[N][K])^T + bias ----------
// EPI=0: fp32 out [M][N].  EPI=1: scatter qkv -> q/k/v bf16 [B,H,T,D], q pre-scaled by 1/8.
template<int EPI>
__global__ __launch_bounds__(256)
void gemm_bf16(const float* __restrict__ A, const ushort* __restrict__ BT,
               const float* __restrict__ bias, float* __restrict__ outF,
               ushort* __restrict__ qd, ushort* __restrict__ kd, ushort* __restrict__ vd,
               int M, int N, int K)
{
  __shared__ ushort As[128][40];   // BK=32 + 8 pad
  __shared__ ushort Bs[128][40];
  const int t = threadIdx.x;
  const int lane = t & 63, wv = t >> 6;
  const int cc = lane & 15, gg = lane >> 4;
  const int m0 = blockIdx.y * 128, n0 = blockIdx.x * 128;
  const int wm = (wv >> 1) * 64, wn = (wv & 1) * 64;
  const int srow = t >> 1, scol = (t & 1) * 16;

  f32x4 acc[4][4];
#pragma unroll
  for (int i = 0; i < 4; ++i)
#pragma unroll
    for (int j = 0; j < 4; ++j) acc[i][j] = (f32x4){0.f, 0.f, 0.f, 0.f};

  const float*  ap = A  + (size_t)(m0 + srow) * K + scol;
  const ushort* bp = BT + (size_t)(n0 + srow) * K + scol;

  for (int kt = 0; kt < K; kt += 32) {
    float4 a0 = *(const float4*)(ap + kt);
    float4 a1 = *(const float4*)(ap + kt + 4);
    float4 a2 = *(const float4*)(ap + kt + 8);
    float4 a3 = *(const float4*)(ap + kt + 12);
    bf16x8 b0 = *(const bf16x8*)(bp + kt);
    bf16x8 b1 = *(const bf16x8*)(bp + kt + 8);
    __syncthreads();   // previous iteration's LDS reads done before overwrite
    bf16x8 w0, w1;
    w0[0] = (short)f2bf(a0.x); w0[1] = (short)f2bf(a0.y);
    w0[2] = (short)f2bf(a0.z); w0[3] = (short)f2bf(a0.w);
    w0[4] = (short)f2bf(a1.x); w0[5] = (short)f2bf(a1.y);
    w0[6] = (short)f2bf(a1.z); w0[7] = (short)f2bf(a1.w);
    w1[0] = (short)f2bf(a2.x); w1[1] = (short)f2bf(a2.y);
    w1[2] = (short)f2bf(a2.z); w1[3] = (short)f2bf(a2.w);
    w1[4] = (short)f2bf(a3.x); w1[5] = (short)f2bf(a3.y);
    w1[6] = (short)f2bf(a3.z); w1[7] = (short)f2bf(a3.w);
    *(bf16x8*)&As[srow][scol]     = w0;
    *(bf16x8*)&As[srow][scol + 8] = w1;
    *(bf16x8*)&Bs[srow][scol]     = b0;
    *(bf16x8*)&Bs[srow][scol + 8] = b1;
    __syncthreads();
    bf16x8 fa[4], fb[4];
#pragma unroll
    for (int i = 0; i < 4; ++i) fa[i] = *(const bf16x8*)&As[wm + i * 16 + cc][8 * gg];
#pragma unroll
    for (int j = 0; j < 4; ++j) fb[j] = *(const bf16x8*)&Bs[wn + j * 16 + cc][8 * gg];
#pragma unroll
    for (int i = 0; i < 4; ++i)
#pragma unroll
      for (int j = 0; j < 4; ++j)
        acc[i][j] = __builtin_amdgcn_mfma_f32_16x16x32_bf16(fa[i], fb[j], acc[i][j], 0, 0, 0);
  }

#pragma unroll
  for (int i = 0; i < 4; ++i) {
#pragma unroll
    for (int j = 0; j < 4; ++j) {
      int gm0 = m0 + wm + i * 16 + gg * 4;
      int gn  = n0 + wn + j * 16 + cc;
      float bv = bias[gn];
      if (EPI == 0) {
#pragma unroll
        for (int e = 0; e < 4; ++e)
          outF[(size_t)(gm0 + e) * N + gn] = acc[i][j][e] + bv;
      } else {
        int which = gn / CEMB;
        int r = gn - which * CEMB;
        int hh = r >> 6, dd = r & 63;
        ushort* dst = which == 0 ? qd : (which == 1 ? kd : vd);
        float sc = (which == 0) ? 0.125f : 1.0f;   // fold 1/sqrt(D) into Q (exact)
#pragma unroll
        for (int e = 0; e < 4; ++e) {
          int gm = gm0 + e;
          int tt = gm & (TSEQ - 1), bb = gm >> 11;
          dst[(size_t)((bb * NHEAD + hh) * TSEQ + tt) * DHEAD + dd] = f2bf((acc[i][j][e] + bv) * sc);
        }
      }
    }
  }
}

// ---------- flash attention (LDS-staged K/V, double-buffered, swizzled) ----------
// Block bx handles q-tiles bx and NT-1-bx (balanced). All 4 waves share K/V tiles:
// staged once per block via global_load_lds (width 16), pre-swizzled global source
// (rule 21: linear LDS dest + src-permute + same XOR on read). XOR: colbyte ^= (row&7)<<4.
// S^T = mfma(K,Q) (lane-local q-row softmax); PV as O^T = mfma(V^T, P).
__global__ __launch_bounds__(256)
void attn_fwd(const ushort* __restrict__ qg, const ushort* __restrict__ kg,
              const ushort* __restrict__ vTg, float* __restrict__ ybuf)
{
  // LDS: K[2] @ 0 (each 64 rows x 128B, swizzled), V[2] @ 16384, P @ 32768 (4 waves x [16][80])
  __shared__ __align__(16) char smem[43008];
  const int t = threadIdx.x, lane = t & 63, w = t >> 6;
  const int cc = lane & 15, gg = lane >> 4;
  const int NT = TSEQ / 64;
  const int bx = blockIdx.x, bh = blockIdx.y;
  const int b = bh / NHEAD, h = bh - b * NHEAD;

  const char* Kg = (const char*)(kg + (size_t)bh * TSEQ * DHEAD);   // [T][64] rows, 128B stride
  const char* Vg = (const char*)(vTg + (size_t)bh * TSEQ * DHEAD);  // [64][T] rows, 4096B stride

  // staging geometry: chunk c = w*2+i covers LDS bytes [c*1024, +1024) = rows c*8..c*8+7
  const int srow = lane >> 3;           // lane's sub-row in its 8-row chunk (= row&7)
  const int ssw  = ((lane & 7) * 16) ^ (srow << 4);  // pre-swizzled source colbyte

  ushort* Pw = (ushort*)(smem + 32768 + w * 2560);   // wave-private [16][80]

  auto stage = [&](int pp, int kt) {
#pragma unroll
    for (int i = 0; i < 2; ++i) {
      const int c = w * 2 + i;
      const char* gk = Kg + (size_t)(kt * 64 + c * 8 + srow) * 128 + ssw;
      __builtin_amdgcn_global_load_lds(
          (const __attribute__((address_space(1))) unsigned*)gk,
          (__attribute__((address_space(3))) unsigned*)(smem + pp * 8192 + c * 1024),
          16, 0, 0);
      const char* gv = Vg + (size_t)(c * 8 + srow) * (TSEQ * 2) + (size_t)kt * 128 + ssw;
      __builtin_amdgcn_global_load_lds(
          (const __attribute__((address_space(1))) unsigned*)gv,
          (__attribute__((address_space(3))) unsigned*)(smem + 16384 + pp * 8192 + c * 1024),
          16, 0, 0);
    }
  };

  int p = 0;
  for (int pass = 0; pass < 2; ++pass) {
    const int qt = pass ? (NT - 1 - bx) : bx;
    const int qrow0 = qt * 64 + w * 16;

    const ushort* Qp = qg + ((size_t)bh * TSEQ + qrow0) * DHEAD;
    bf16x8 fq0 = *(const bf16x8*)(Qp + cc * DHEAD + 8 * gg);
    bf16x8 fq1 = *(const bf16x8*)(Qp + cc * DHEAD + 32 + 8 * gg);

    f32x4 o[4];   // O^T: o[dt][e] = O^T[d = dt*16 + gg*4 + e, q = cc]
#pragma unroll
    for (int i = 0; i < 4; ++i) o[i] = (f32x4){0.f, 0.f, 0.f, 0.f};
    float m = -1e30f, l = 0.f;

    stage(p, 0);
    asm volatile("s_waitcnt vmcnt(0)" ::: "memory");
    __syncthreads();

    for (int kt = 0; kt <= qt; ++kt) {
      if (kt < qt) stage(p ^ 1, kt + 1);   // prefetch next tile; lands by end-of-iter barrier

      const char* Kl = smem + p * 8192;
      const char* Vl = smem + 16384 + p * 8192;
      f32x4 st[4];   // st[ct][e] = S^T[key = 16ct + 4gg + e, q = cc]
#pragma unroll
      for (int ct = 0; ct < 4; ++ct) st[ct] = (f32x4){0.f, 0.f, 0.f, 0.f};
      __builtin_amdgcn_s_setprio(1);
#pragma unroll
      for (int ct = 0; ct < 4; ++ct) {
        const int r = ct * 16 + cc;
        const char* kb = Kl + r * 128;
        bf16x8 fk0 = *(const bf16x8*)(kb + ((gg * 16) ^ ((r & 7) << 4)));
        bf16x8 fk1 = *(const bf16x8*)(kb + ((64 + gg * 16) ^ ((r & 7) << 4)));
        st[ct] = __builtin_amdgcn_mfma_f32_16x16x32_bf16(fk0, fq0, st[ct], 0, 0, 0);
        st[ct] = __builtin_amdgcn_mfma_f32_16x16x32_bf16(fk1, fq1, st[ct], 0, 0, 0);
      }
      __builtin_amdgcn_s_setprio(0);

      if (kt == qt) {   // causal mask on diagonal tile (Q pre-scaled by 1/8)
#pragma unroll
        for (int ct = 0; ct < 4; ++ct)
#pragma unroll
          for (int e = 0; e < 4; ++e)
            if (ct * 16 + gg * 4 + e > w * 16 + cc) st[ct][e] = -1e30f;
      }
      float ml = st[0][0];
#pragma unroll
      for (int ct = 0; ct < 4; ++ct)
#pragma unroll
        for (int e = 0; e < 4; ++e) ml = fmaxf(ml, st[ct][e]);
      ml = fmaxf(ml, __shfl_xor(ml, 16, 64));
      ml = fmaxf(ml, __shfl_xor(ml, 32, 64));
      float mn = fmaxf(m, ml);
      float al = __expf(m - mn);
      float ps = 0.f;
#pragma unroll
      for (int ct = 0; ct < 4; ++ct)
#pragma unroll
        for (int e = 0; e < 4; ++e) { float pp = __expf(st[ct][e] - mn); st[ct][e] = pp; ps += pp; }
#pragma unroll
      for (int ct = 0; ct < 4; ++ct) {
        uint2 pw;
        pw.x = (unsigned)f2bf(st[ct][0]) | ((unsigned)f2bf(st[ct][1]) << 16);
        pw.y = (unsigned)f2bf(st[ct][2]) | ((unsigned)f2bf(st[ct][3]) << 16);
        *(uint2*)&Pw[cc * 80 + ct * 16 + gg * 4] = pw;
      }
      ps += __shfl_xor(ps, 16, 64);
      ps += __shfl_xor(ps, 32, 64);
      l = l * al + ps;
      m = mn;
#pragma unroll
      for (int dt = 0; dt < 4; ++dt)
#pragma unroll
        for (int e = 0; e < 4; ++e) o[dt][e] *= al;
      lds_fence();   // wave-local: P writes complete before fragment reads
      __builtin_amdgcn_s_setprio(1);
#pragma unroll
      for (int kc = 0; kc < 2; ++kc) {
        bf16x8 pb = *(const bf16x8*)&Pw[cc * 80 + kc * 32 + 8 * gg];
#pragma unroll
        for (int dt = 0; dt < 4; ++dt) {
          const int rd = dt * 16 + cc;
          bf16x8 fv = *(const bf16x8*)(Vl + rd * 128 + ((kc * 64 + gg * 16) ^ ((rd & 7) << 4)));
          o[dt] = __builtin_amdgcn_mfma_f32_16x16x32_bf16(fv, pb, o[dt], 0, 0, 0);
        }
      }
      __builtin_amdgcn_s_setprio(0);
      asm volatile("s_waitcnt vmcnt(0)" ::: "memory");   // next tile's stage landed
      __syncthreads();                                   // all waves done reading buf p
      p ^= 1;
    }

    float inv = 1.0f / l;
#pragma unroll
    for (int dt = 0; dt < 4; ++dt)
#pragma unroll
      for (int e = 0; e < 4; ++e) {
        int row = qrow0 + cc;
        int col = h * DHEAD + dt * 16 + gg * 4 + e;
        ybuf[((size_t)b * TSEQ + row) * CEMB + col] = o[dt][e] * inv;
      }
  }
}

extern "C" void kernel_launch(void* const* d_in, const int* in_sizes, int n_in,
                              void* d_out, int out_size, void* d_ws, size_t ws_size,
                              hipStream_t stream)
{
  (void)in_sizes; (void)n_in; (void)out_size; (void)ws_size;
  const float* x  = (const float*)d_in[0];
  const float* Wa = (const float*)d_in[1];
  const float* ba = (const float*)d_in[2];
  const float* Wo = (const float*)d_in[3];
  const float* bo = (const float*)d_in[4];
  float* out = (float*)d_out;

  char* p = (char*)d_ws;
  ushort* WaT  = (ushort*)p; p += (size_t)3 * CEMB * CEMB * 2;              // [2304][768] bf16
  ushort* WoT  = (ushort*)p; p += (size_t)CEMB * CEMB * 2;                  // [768][768] bf16
  ushort* qb   = (ushort*)p; p += (size_t)NBATCH * NHEAD * TSEQ * DHEAD * 2; // [B,H,T,D]
  ushort* kb   = (ushort*)p; p += (size_t)NBATCH * NHEAD * TSEQ * DHEAD * 2;
  ushort* vtmp = (ushort*)p; p += (size_t)NBATCH * NHEAD * TSEQ * DHEAD * 2;
  ushort* vT   = (ushort*)p; p += (size_t)NBATCH * NHEAD * TSEQ * DHEAD * 2; // [B,H,D,T]
  float*  yb   = (float*)p;  p += (size_t)NBATCH * TSEQ * CEMB * 4;          // fp32 [B,T,C]

  dim3 tb(32, 8);
  transpose_w<<<dim3(3 * CEMB / 32, CEMB / 32), tb, 0, stream>>>(Wa, WaT, CEMB, 3 * CEMB);
  transpose_w<<<dim3(CEMB / 32, CEMB / 32), tb, 0, stream>>>(Wo, WoT, CEMB, CEMB);
  gemm_bf16<1><<<dim3(3 * CEMB / 128, NBATCH * TSEQ / 128), 256, 0, stream>>>(
      x, WaT, ba, nullptr, qb, kb, vtmp, NBATCH * TSEQ, 3 * CEMB, CEMB);
  transpose_v<<<dim3(TSEQ / 32, DHEAD / 32, NBATCH * NHEAD), tb, 0, stream>>>(vtmp, vT);
  attn_fwd<<<dim3(TSEQ / 128, NBATCH * NHEAD), 256, 0, stream>>>(qb, kb, vT, yb);
  gemm_bf16<0><<<dim3(CEMB / 128, NBATCH * TSEQ / 128), 256, 0, stream>>>(
      yb, WoT, bo, out, nullptr, nullptr, nullptr, NBATCH * TSEQ, CEMB, CEMB);
}

// Round 6
// 156.005 us; speedup vs baseline: 2.8930x; 1.1752x over previous
//
#include <hip/hip_runtime.h>
#include <hip/hip_bf16.h>

#define NHEAD 12
#define TSEQ 2048
#define CEMB 768
#define DHEAD 64
#define NBATCH 4

typedef __attribute__((ext_vector_type(8))) short bf16x8;
typedef __attribute__((ext_vector_type(4))) float f32x4;

__device__ __forceinline__ ushort f2bf(float f) {
  union { float f; unsigned u; } v; v.f = f;
  unsigned u = v.u;
  u += 0x7FFFu + ((u >> 16) & 1u);   // RNE to bf16
  return (ushort)(u >> 16);
}

// wave-local LDS ordering (P buffer is wave-private; no block barrier needed)
__device__ __forceinline__ void lds_fence() {
  asm volatile("s_waitcnt lgkmcnt(0)" ::: "memory");
  __builtin_amdgcn_sched_barrier(0);   // rule 18: pin ops after the waitcnt
}

// ---------- fp32 -> bf16 bulk cast (x) ----------
__global__ __launch_bounds__(256)
void cast_x(const float* __restrict__ src, ushort* __restrict__ dst, int n) {
  int i = (blockIdx.x * 256 + threadIdx.x) * 8;
  if (i < n) {
    float4 v0 = *(const float4*)(src + i);
    float4 v1 = *(const float4*)(src + i + 4);
    bf16x8 w;
    w[0] = (short)f2bf(v0.x); w[1] = (short)f2bf(v0.y);
    w[2] = (short)f2bf(v0.z); w[3] = (short)f2bf(v0.w);
    w[4] = (short)f2bf(v1.x); w[5] = (short)f2bf(v1.y);
    w[6] = (short)f2bf(v1.z); w[7] = (short)f2bf(v1.w);
    *(bf16x8*)(dst + i) = w;
  }
}

// ---------- fp32 [R][C] -> bf16 [C][R] (weight pre-transpose) ----------
__global__ void transpose_w(const float* __restrict__ src, ushort* __restrict__ dst,
                            int R, int C) {
  __shared__ float tile[32][33];
  int c0 = blockIdx.x * 32, r0 = blockIdx.y * 32;
  int tx = threadIdx.x, ty = threadIdx.y;  // block (32,8)
#pragma unroll
  for (int j = 0; j < 4; ++j)
    tile[ty + j * 8][tx] = src[(size_t)(r0 + ty + j * 8) * C + c0 + tx];
  __syncthreads();
#pragma unroll
  for (int j = 0; j < 4; ++j)
    dst[(size_t)(c0 + ty + j * 8) * R + r0 + tx] = f2bf(tile[tx][ty + j * 8]);
}

// ---------- bf16 v [BH][T][D] -> vT [BH][D][T] ----------
__global__ void transpose_v(const ushort* __restrict__ src, ushort* __restrict__ dst) {
  __shared__ ushort tile[32][33];
  int bh = blockIdx.z;
  int t0 = blockIdx.x * 32, d0 = blockIdx.y * 32;
  int tx = threadIdx.x, ty = threadIdx.y;  // block (32,8)
  const ushort* s = src + (size_t)bh * TSEQ * DHEAD;
  ushort* o = dst + (size_t)bh * TSEQ * DHEAD;
#pragma unroll
  for (int j = 0; j < 4; ++j)
    tile[ty + j * 8][tx] = s[(t0 + ty + j * 8) * DHEAD + d0 + tx];
  __syncthreads();
#pragma unroll
  for (int j = 0; j < 4; ++j)
    o[(size_t)(d0 + ty + j * 8) * TSEQ + t0 + tx] = tile[tx][ty + j * 8];
}

// ---------- bf16 MFMA GEMM (m97 structure): C[M][N] = A(bf16,[M][K]) * BT(bf16,[N][K])^T + bias
// A and B tiles staged via global_load_lds width=16 (linear LDS dest), slot-XOR swizzle
// s ^= (row>>1)&3 pre-applied on the GLOBAL source + same XOR on the ds_read side (rule 21).
// EPI=0: fp32 out [M][N].  EPI=1: scatter qkv -> q/k/v bf16 [B,H,T,D], q pre-scaled by 1/8.
template<int EPI>
__global__ __launch_bounds__(256)
void gemm_bf16(const ushort* __restrict__ A, const ushort* __restrict__ BT,
               const float* __restrict__ bias, float* __restrict__ outF,
               ushort* __restrict__ qd, ushort* __restrict__ kd, ushort* __restrict__ vd,
               int M, int N, int K)
{
  __shared__ __align__(16) char smem[16384];   // As 8KB @0, Bs 8KB @8192
  const int t = threadIdx.x;
  const int lane = t & 63, wv = t >> 6;
  const int cc = lane & 15, gg = lane >> 4;
  const int m0 = blockIdx.y * 128, n0 = blockIdx.x * 128;
  const int wm = (wv >> 1) * 64, wn = (wv & 1) * 64;

  // staging: thread covers LDS linear offsets o0 = wv*1024 + lane*16 and o0 + 4096.
  // LDS(row, slot) holds G(row, slot ^ ((row>>1)&3));  row = o>>6 (64B rows), slot = (o>>4)&3
  const int o0 = wv * 1024 + lane * 16;
  const int o1 = o0 + 4096;
  const int r0s = o0 >> 6, s0s = (o0 >> 4) & 3;
  const int r1s = o1 >> 6, s1s = (o1 >> 4) & 3;
  const size_t Kb = (size_t)K * 2;
  const char* a0p = (const char*)A  + (size_t)(m0 + r0s) * Kb + ((s0s ^ ((r0s >> 1) & 3)) << 4);
  const char* a1p = (const char*)A  + (size_t)(m0 + r1s) * Kb + ((s1s ^ ((r1s >> 1) & 3)) << 4);
  const char* b0p = (const char*)BT + (size_t)(n0 + r0s) * Kb + ((s0s ^ ((r0s >> 1) & 3)) << 4);
  const char* b1p = (const char*)BT + (size_t)(n0 + r1s) * Kb + ((s1s ^ ((r1s >> 1) & 3)) << 4);

  char* As = smem;
  char* Bs = smem + 8192;

  f32x4 acc[4][4];
#pragma unroll
  for (int i = 0; i < 4; ++i)
#pragma unroll
    for (int j = 0; j < 4; ++j) acc[i][j] = (f32x4){0.f, 0.f, 0.f, 0.f};

  const int KB = K * 2;   // row bytes
  for (int kb = 0; kb < KB; kb += 64) {
    __builtin_amdgcn_global_load_lds(
        (const __attribute__((address_space(1))) unsigned*)(a0p + kb),
        (__attribute__((address_space(3))) unsigned*)(As + wv * 1024), 16, 0, 0);
    __builtin_amdgcn_global_load_lds(
        (const __attribute__((address_space(1))) unsigned*)(a1p + kb),
        (__attribute__((address_space(3))) unsigned*)(As + wv * 1024 + 4096), 16, 0, 0);
    __builtin_amdgcn_global_load_lds(
        (const __attribute__((address_space(1))) unsigned*)(b0p + kb),
        (__attribute__((address_space(3))) unsigned*)(Bs + wv * 1024), 16, 0, 0);
    __builtin_amdgcn_global_load_lds(
        (const __attribute__((address_space(1))) unsigned*)(b1p + kb),
        (__attribute__((address_space(3))) unsigned*)(Bs + wv * 1024 + 4096), 16, 0, 0);
    __syncthreads();   // drains vmcnt(0): staged tile visible to all waves
    bf16x8 fa[4], fb[4];
#pragma unroll
    for (int i = 0; i < 4; ++i) {
      const int r = wm + i * 16 + cc;
      fa[i] = *(const bf16x8*)(As + r * 64 + ((gg ^ ((r >> 1) & 3)) << 4));
    }
#pragma unroll
    for (int j = 0; j < 4; ++j) {
      const int r = wn + j * 16 + cc;
      fb[j] = *(const bf16x8*)(Bs + r * 64 + ((gg ^ ((r >> 1) & 3)) << 4));
    }
    __builtin_amdgcn_s_setprio(1);
#pragma unroll
    for (int i = 0; i < 4; ++i)
#pragma unroll
      for (int j = 0; j < 4; ++j)
        acc[i][j] = __builtin_amdgcn_mfma_f32_16x16x32_bf16(fa[i], fb[j], acc[i][j], 0, 0, 0);
    __builtin_amdgcn_s_setprio(0);
    __syncthreads();   // all reads done before next stage overwrites
  }

#pragma unroll
  for (int i = 0; i < 4; ++i) {
#pragma unroll
    for (int j = 0; j < 4; ++j) {
      int gm0 = m0 + wm + i * 16 + gg * 4;
      int gn  = n0 + wn + j * 16 + cc;
      float bv = bias[gn];
      if (EPI == 0) {
#pragma unroll
        for (int e = 0; e < 4; ++e)
          outF[(size_t)(gm0 + e) * N + gn] = acc[i][j][e] + bv;
      } else {
        int which = gn / CEMB;
        int r = gn - which * CEMB;
        int hh = r >> 6, dd = r & 63;
        ushort* dst = which == 0 ? qd : (which == 1 ? kd : vd);
        float sc = (which == 0) ? 0.125f : 1.0f;   // fold 1/sqrt(D) into Q (exact)
#pragma unroll
        for (int e = 0; e < 4; ++e) {
          int gm = gm0 + e;
          int tt = gm & (TSEQ - 1), bb = gm >> 11;
          dst[(size_t)((bb * NHEAD + hh) * TSEQ + tt) * DHEAD + dd] = f2bf((acc[i][j][e] + bv) * sc);
        }
      }
    }
  }
}

// ---------- flash attention (LDS-staged K/V, double-buffered, swizzled) ----------
// Block bx handles q-tiles bx and NT-1-bx (balanced). All 4 waves share K/V tiles:
// staged once per block via global_load_lds (width 16), pre-swizzled global source
// (rule 21: linear LDS dest + src-permute + same XOR on read). XOR: colbyte ^= (row&7)<<4.
// S^T = mfma(K,Q) (lane-local q-row softmax); PV as O^T = mfma(V^T, P). Output bf16.
__global__ __launch_bounds__(256)
void attn_fwd(const ushort* __restrict__ qg, const ushort* __restrict__ kg,
              const ushort* __restrict__ vTg, ushort* __restrict__ ybb)
{
  // LDS: K[2] @ 0 (each 64 rows x 128B, swizzled), V[2] @ 16384, P @ 32768 (4 waves x [16][80])
  __shared__ __align__(16) char smem[43008];
  const int t = threadIdx.x, lane = t & 63, w = t >> 6;
  const int cc = lane & 15, gg = lane >> 4;
  const int NT = TSEQ / 64;
  const int bx = blockIdx.x, bh = blockIdx.y;
  const int b = bh / NHEAD, h = bh - b * NHEAD;

  const char* Kg = (const char*)(kg + (size_t)bh * TSEQ * DHEAD);   // [T][64] rows, 128B stride
  const char* Vg = (const char*)(vTg + (size_t)bh * TSEQ * DHEAD);  // [64][T] rows, 4096B stride

  // staging geometry: chunk c = w*2+i covers LDS bytes [c*1024, +1024) = rows c*8..c*8+7
  const int srow = lane >> 3;           // lane's sub-row in its 8-row chunk (= row&7)
  const int ssw  = ((lane & 7) * 16) ^ (srow << 4);  // pre-swizzled source colbyte

  ushort* Pw = (ushort*)(smem + 32768 + w * 2560);   // wave-private [16][80]

  auto stage = [&](int pp, int kt) {
#pragma unroll
    for (int i = 0; i < 2; ++i) {
      const int c = w * 2 + i;
      const char* gk = Kg + (size_t)(kt * 64 + c * 8 + srow) * 128 + ssw;
      __builtin_amdgcn_global_load_lds(
          (const __attribute__((address_space(1))) unsigned*)gk,
          (__attribute__((address_space(3))) unsigned*)(smem + pp * 8192 + c * 1024),
          16, 0, 0);
      const char* gv = Vg + (size_t)(c * 8 + srow) * (TSEQ * 2) + (size_t)kt * 128 + ssw;
      __builtin_amdgcn_global_load_lds(
          (const __attribute__((address_space(1))) unsigned*)gv,
          (__attribute__((address_space(3))) unsigned*)(smem + 16384 + pp * 8192 + c * 1024),
          16, 0, 0);
    }
  };

  int p = 0;
  for (int pass = 0; pass < 2; ++pass) {
    const int qt = pass ? (NT - 1 - bx) : bx;
    const int qrow0 = qt * 64 + w * 16;

    const ushort* Qp = qg + ((size_t)bh * TSEQ + qrow0) * DHEAD;
    bf16x8 fq0 = *(const bf16x8*)(Qp + cc * DHEAD + 8 * gg);
    bf16x8 fq1 = *(const bf16x8*)(Qp + cc * DHEAD + 32 + 8 * gg);

    f32x4 o[4];   // O^T: o[dt][e] = O^T[d = dt*16 + gg*4 + e, q = cc]
#pragma unroll
    for (int i = 0; i < 4; ++i) o[i] = (f32x4){0.f, 0.f, 0.f, 0.f};
    float m = -1e30f, l = 0.f;

    stage(p, 0);
    asm volatile("s_waitcnt vmcnt(0)" ::: "memory");
    __syncthreads();

    for (int kt = 0; kt <= qt; ++kt) {
      if (kt < qt) stage(p ^ 1, kt + 1);   // prefetch next tile; lands by end-of-iter barrier

      const char* Kl = smem + p * 8192;
      const char* Vl = smem + 16384 + p * 8192;
      f32x4 st[4];   // st[ct][e] = S^T[key = 16ct + 4gg + e, q = cc]
#pragma unroll
      for (int ct = 0; ct < 4; ++ct) st[ct] = (f32x4){0.f, 0.f, 0.f, 0.f};
      __builtin_amdgcn_s_setprio(1);
#pragma unroll
      for (int ct = 0; ct < 4; ++ct) {
        const int r = ct * 16 + cc;
        const char* kb = Kl + r * 128;
        bf16x8 fk0 = *(const bf16x8*)(kb + ((gg * 16) ^ ((r & 7) << 4)));
        bf16x8 fk1 = *(const bf16x8*)(kb + ((64 + gg * 16) ^ ((r & 7) << 4)));
        st[ct] = __builtin_amdgcn_mfma_f32_16x16x32_bf16(fk0, fq0, st[ct], 0, 0, 0);
        st[ct] = __builtin_amdgcn_mfma_f32_16x16x32_bf16(fk1, fq1, st[ct], 0, 0, 0);
      }
      __builtin_amdgcn_s_setprio(0);

      if (kt == qt) {   // causal mask on diagonal tile (Q pre-scaled by 1/8)
#pragma unroll
        for (int ct = 0; ct < 4; ++ct)
#pragma unroll
          for (int e = 0; e < 4; ++e)
            if (ct * 16 + gg * 4 + e > w * 16 + cc) st[ct][e] = -1e30f;
      }
      float ml = st[0][0];
#pragma unroll
      for (int ct = 0; ct < 4; ++ct)
#pragma unroll
        for (int e = 0; e < 4; ++e) ml = fmaxf(ml, st[ct][e]);
      ml = fmaxf(ml, __shfl_xor(ml, 16, 64));
      ml = fmaxf(ml, __shfl_xor(ml, 32, 64));
      float mn = fmaxf(m, ml);
      float al = __expf(m - mn);
      float ps = 0.f;
#pragma unroll
      for (int ct = 0; ct < 4; ++ct)
#pragma unroll
        for (int e = 0; e < 4; ++e) { float pp = __expf(st[ct][e] - mn); st[ct][e] = pp; ps += pp; }
#pragma unroll
      for (int ct = 0; ct < 4; ++ct) {
        uint2 pw;
        pw.x = (unsigned)f2bf(st[ct][0]) | ((unsigned)f2bf(st[ct][1]) << 16);
        pw.y = (unsigned)f2bf(st[ct][2]) | ((unsigned)f2bf(st[ct][3]) << 16);
        *(uint2*)&Pw[cc * 80 + ct * 16 + gg * 4] = pw;
      }
      ps += __shfl_xor(ps, 16, 64);
      ps += __shfl_xor(ps, 32, 64);
      l = l * al + ps;
      m = mn;
#pragma unroll
      for (int dt = 0; dt < 4; ++dt)
#pragma unroll
        for (int e = 0; e < 4; ++e) o[dt][e] *= al;
      lds_fence();   // wave-local: P writes complete before fragment reads
      __builtin_amdgcn_s_setprio(1);
#pragma unroll
      for (int kc = 0; kc < 2; ++kc) {
        bf16x8 pb = *(const bf16x8*)&Pw[cc * 80 + kc * 32 + 8 * gg];
#pragma unroll
        for (int dt = 0; dt < 4; ++dt) {
          const int rd = dt * 16 + cc;
          bf16x8 fv = *(const bf16x8*)(Vl + rd * 128 + ((kc * 64 + gg * 16) ^ ((rd & 7) << 4)));
          o[dt] = __builtin_amdgcn_mfma_f32_16x16x32_bf16(fv, pb, o[dt], 0, 0, 0);
        }
      }
      __builtin_amdgcn_s_setprio(0);
      asm volatile("s_waitcnt vmcnt(0)" ::: "memory");   // next tile's stage landed
      __syncthreads();                                   // all waves done reading buf p
      p ^= 1;
    }

    float inv = 1.0f / l;
    ushort* yrow = ybb + (size_t)(b * TSEQ + qrow0 + cc) * CEMB + h * DHEAD;
#pragma unroll
    for (int dt = 0; dt < 4; ++dt) {
      uint2 pw;
      pw.x = (unsigned)f2bf(o[dt][0] * inv) | ((unsigned)f2bf(o[dt][1] * inv) << 16);
      pw.y = (unsigned)f2bf(o[dt][2] * inv) | ((unsigned)f2bf(o[dt][3] * inv) << 16);
      *(uint2*)(yrow + dt * 16 + gg * 4) = pw;
    }
  }
}

extern "C" void kernel_launch(void* const* d_in, const int* in_sizes, int n_in,
                              void* d_out, int out_size, void* d_ws, size_t ws_size,
                              hipStream_t stream)
{
  (void)in_sizes; (void)n_in; (void)out_size; (void)ws_size;
  const float* x  = (const float*)d_in[0];
  const float* Wa = (const float*)d_in[1];
  const float* ba = (const float*)d_in[2];
  const float* Wo = (const float*)d_in[3];
  const float* bo = (const float*)d_in[4];
  float* out = (float*)d_out;

  char* p = (char*)d_ws;
  ushort* WaT  = (ushort*)p; p += (size_t)3 * CEMB * CEMB * 2;               // [2304][768] bf16
  ushort* WoT  = (ushort*)p; p += (size_t)CEMB * CEMB * 2;                   // [768][768] bf16
  ushort* xb   = (ushort*)p; p += (size_t)NBATCH * TSEQ * CEMB * 2;          // x bf16 [B*T][C]
  ushort* qb   = (ushort*)p; p += (size_t)NBATCH * NHEAD * TSEQ * DHEAD * 2; // [B,H,T,D]
  ushort* kb   = (ushort*)p; p += (size_t)NBATCH * NHEAD * TSEQ * DHEAD * 2;
  ushort* vtmp = (ushort*)p; p += (size_t)NBATCH * NHEAD * TSEQ * DHEAD * 2;
  ushort* vT   = (ushort*)p; p += (size_t)NBATCH * NHEAD * TSEQ * DHEAD * 2; // [B,H,D,T]
  ushort* yb   = (ushort*)p; p += (size_t)NBATCH * TSEQ * CEMB * 2;          // attn out bf16 [B*T][C]

  dim3 tb(32, 8);
  cast_x<<<NBATCH * TSEQ * CEMB / (256 * 8), 256, 0, stream>>>(x, xb, NBATCH * TSEQ * CEMB);
  transpose_w<<<dim3(3 * CEMB / 32, CEMB / 32), tb, 0, stream>>>(Wa, WaT, CEMB, 3 * CEMB);
  transpose_w<<<dim3(CEMB / 32, CEMB / 32), tb, 0, stream>>>(Wo, WoT, CEMB, CEMB);
  gemm_bf16<1><<<dim3(3 * CEMB / 128, NBATCH * TSEQ / 128), 256, 0, stream>>>(
      xb, WaT, ba, nullptr, qb, kb, vtmp, NBATCH * TSEQ, 3 * CEMB, CEMB);
  transpose_v<<<dim3(TSEQ / 32, DHEAD / 32, NBATCH * NHEAD), tb, 0, stream>>>(vtmp, vT);
  attn_fwd<<<dim3(TSEQ / 128, NBATCH * NHEAD), 256, 0, stream>>>(qb, kb, vT, yb);
  gemm_bf16<0><<<dim3(CEMB / 128, NBATCH * TSEQ / 128), 256, 0, stream>>>(
      yb, WoT, bo, out, nullptr, nullptr, nullptr, NBATCH * TSEQ, CEMB, CEMB);
}

// Round 7
// 153.411 us; speedup vs baseline: 2.9420x; 1.0169x over previous
//
#include <hip/hip_runtime.h>
#include <hip/hip_bf16.h>

#define NHEAD 12
#define TSEQ 2048
#define CEMB 768
#define DHEAD 64
#define NBATCH 4

typedef __attribute__((ext_vector_type(8))) short bf16x8;
typedef __attribute__((ext_vector_type(4))) float f32x4;

__device__ __forceinline__ ushort f2bf(float f) {
  union { float f; unsigned u; } v; v.f = f;
  unsigned u = v.u;
  u += 0x7FFFu + ((u >> 16) & 1u);   // RNE to bf16
  return (ushort)(u >> 16);
}

// packed f32x2 -> bf16x2 (1 inst, RNE) — T12 primitive
__device__ __forceinline__ unsigned cvt_pk_bf16(float lo, float hi) {
  unsigned r;
  asm("v_cvt_pk_bf16_f32 %0, %1, %2" : "=v"(r) : "v"(lo), "v"(hi));
  return r;
}

// wave-local LDS ordering (P buffer is wave-private; no block barrier needed)
__device__ __forceinline__ void lds_fence() {
  asm volatile("s_waitcnt lgkmcnt(0)" ::: "memory");
  __builtin_amdgcn_sched_barrier(0);   // rule 18: pin ops after the waitcnt
}

// ---------- fp32 -> bf16 bulk cast (x) ----------
__global__ __launch_bounds__(256)
void cast_x(const float* __restrict__ src, ushort* __restrict__ dst, int n) {
  int i = (blockIdx.x * 256 + threadIdx.x) * 8;
  if (i < n) {
    float4 v0 = *(const float4*)(src + i);
    float4 v1 = *(const float4*)(src + i + 4);
    bf16x8 w;
    w[0] = (short)f2bf(v0.x); w[1] = (short)f2bf(v0.y);
    w[2] = (short)f2bf(v0.z); w[3] = (short)f2bf(v0.w);
    w[4] = (short)f2bf(v1.x); w[5] = (short)f2bf(v1.y);
    w[6] = (short)f2bf(v1.z); w[7] = (short)f2bf(v1.w);
    *(bf16x8*)(dst + i) = w;
  }
}

// ---------- fp32 [R][C] -> bf16 [C][R] (weight pre-transpose) ----------
__global__ void transpose_w(const float* __restrict__ src, ushort* __restrict__ dst,
                            int R, int C) {
  __shared__ float tile[32][33];
  int c0 = blockIdx.x * 32, r0 = blockIdx.y * 32;
  int tx = threadIdx.x, ty = threadIdx.y;  // block (32,8)
#pragma unroll
  for (int j = 0; j < 4; ++j)
    tile[ty + j * 8][tx] = src[(size_t)(r0 + ty + j * 8) * C + c0 + tx];
  __syncthreads();
#pragma unroll
  for (int j = 0; j < 4; ++j)
    dst[(size_t)(c0 + ty + j * 8) * R + r0 + tx] = f2bf(tile[tx][ty + j * 8]);
}

// ---------- bf16 v [BH][T][D] -> vT [BH][D][T] ----------
__global__ void transpose_v(const ushort* __restrict__ src, ushort* __restrict__ dst) {
  __shared__ ushort tile[32][33];
  int bh = blockIdx.z;
  int t0 = blockIdx.x * 32, d0 = blockIdx.y * 32;
  int tx = threadIdx.x, ty = threadIdx.y;  // block (32,8)
  const ushort* s = src + (size_t)bh * TSEQ * DHEAD;
  ushort* o = dst + (size_t)bh * TSEQ * DHEAD;
#pragma unroll
  for (int j = 0; j < 4; ++j)
    tile[ty + j * 8][tx] = s[(t0 + ty + j * 8) * DHEAD + d0 + tx];
  __syncthreads();
#pragma unroll
  for (int j = 0; j < 4; ++j)
    o[(size_t)(d0 + ty + j * 8) * TSEQ + t0 + tx] = tile[tx][ty + j * 8];
}

// ---------- bf16 MFMA GEMM (m97 structure): C[M][N] = A(bf16,[M][K]) * BT(bf16,[N][K])^T + bias
// A and B tiles staged via global_load_lds width=16 (linear LDS dest), slot-XOR swizzle
// s ^= (row>>1)&3 pre-applied on the GLOBAL source + same XOR on the ds_read side (rule 21).
// EPI=0: fp32 out [M][N].  EPI=1: scatter qkv -> q/k/v bf16 [B,H,T,D], q pre-scaled by 1/8.
template<int EPI>
__global__ __launch_bounds__(256)
void gemm_bf16(const ushort* __restrict__ A, const ushort* __restrict__ BT,
               const float* __restrict__ bias, float* __restrict__ outF,
               ushort* __restrict__ qd, ushort* __restrict__ kd, ushort* __restrict__ vd,
               int M, int N, int K)
{
  __shared__ __align__(16) char smem[16384];   // As 8KB @0, Bs 8KB @8192
  const int t = threadIdx.x;
  const int lane = t & 63, wv = t >> 6;
  const int cc = lane & 15, gg = lane >> 4;
  const int m0 = blockIdx.y * 128, n0 = blockIdx.x * 128;
  const int wm = (wv >> 1) * 64, wn = (wv & 1) * 64;

  // staging: thread covers LDS linear offsets o0 = wv*1024 + lane*16 and o0 + 4096.
  // LDS(row, slot) holds G(row, slot ^ ((row>>1)&3));  row = o>>6 (64B rows), slot = (o>>4)&3
  const int o0 = wv * 1024 + lane * 16;
  const int o1 = o0 + 4096;
  const int r0s = o0 >> 6, s0s = (o0 >> 4) & 3;
  const int r1s = o1 >> 6, s1s = (o1 >> 4) & 3;
  const size_t Kb = (size_t)K * 2;
  const char* a0p = (const char*)A  + (size_t)(m0 + r0s) * Kb + ((s0s ^ ((r0s >> 1) & 3)) << 4);
  const char* a1p = (const char*)A  + (size_t)(m0 + r1s) * Kb + ((s1s ^ ((r1s >> 1) & 3)) << 4);
  const char* b0p = (const char*)BT + (size_t)(n0 + r0s) * Kb + ((s0s ^ ((r0s >> 1) & 3)) << 4);
  const char* b1p = (const char*)BT + (size_t)(n0 + r1s) * Kb + ((s1s ^ ((r1s >> 1) & 3)) << 4);

  char* As = smem;
  char* Bs = smem + 8192;

  f32x4 acc[4][4];
#pragma unroll
  for (int i = 0; i < 4; ++i)
#pragma unroll
    for (int j = 0; j < 4; ++j) acc[i][j] = (f32x4){0.f, 0.f, 0.f, 0.f};

  const int KB = K * 2;   // row bytes
  for (int kb = 0; kb < KB; kb += 64) {
    __builtin_amdgcn_global_load_lds(
        (const __attribute__((address_space(1))) unsigned*)(a0p + kb),
        (__attribute__((address_space(3))) unsigned*)(As + wv * 1024), 16, 0, 0);
    __builtin_amdgcn_global_load_lds(
        (const __attribute__((address_space(1))) unsigned*)(a1p + kb),
        (__attribute__((address_space(3))) unsigned*)(As + wv * 1024 + 4096), 16, 0, 0);
    __builtin_amdgcn_global_load_lds(
        (const __attribute__((address_space(1))) unsigned*)(b0p + kb),
        (__attribute__((address_space(3))) unsigned*)(Bs + wv * 1024), 16, 0, 0);
    __builtin_amdgcn_global_load_lds(
        (const __attribute__((address_space(1))) unsigned*)(b1p + kb),
        (__attribute__((address_space(3))) unsigned*)(Bs + wv * 1024 + 4096), 16, 0, 0);
    __syncthreads();   // drains vmcnt(0): staged tile visible to all waves
    bf16x8 fa[4], fb[4];
#pragma unroll
    for (int i = 0; i < 4; ++i) {
      const int r = wm + i * 16 + cc;
      fa[i] = *(const bf16x8*)(As + r * 64 + ((gg ^ ((r >> 1) & 3)) << 4));
    }
#pragma unroll
    for (int j = 0; j < 4; ++j) {
      const int r = wn + j * 16 + cc;
      fb[j] = *(const bf16x8*)(Bs + r * 64 + ((gg ^ ((r >> 1) & 3)) << 4));
    }
    __builtin_amdgcn_s_setprio(1);
#pragma unroll
    for (int i = 0; i < 4; ++i)
#pragma unroll
      for (int j = 0; j < 4; ++j)
        acc[i][j] = __builtin_amdgcn_mfma_f32_16x16x32_bf16(fa[i], fb[j], acc[i][j], 0, 0, 0);
    __builtin_amdgcn_s_setprio(0);
    __syncthreads();   // all reads done before next stage overwrites
  }

#pragma unroll
  for (int i = 0; i < 4; ++i) {
#pragma unroll
    for (int j = 0; j < 4; ++j) {
      int gm0 = m0 + wm + i * 16 + gg * 4;
      int gn  = n0 + wn + j * 16 + cc;
      float bv = bias[gn];
      if (EPI == 0) {
#pragma unroll
        for (int e = 0; e < 4; ++e)
          outF[(size_t)(gm0 + e) * N + gn] = acc[i][j][e] + bv;
      } else {
        int which = gn / CEMB;
        int r = gn - which * CEMB;
        int hh = r >> 6, dd = r & 63;
        ushort* dst = which == 0 ? qd : (which == 1 ? kd : vd);
        float sc = (which == 0) ? 0.125f : 1.0f;   // fold 1/sqrt(D) into Q (exact)
#pragma unroll
        for (int e = 0; e < 4; ++e) {
          int gm = gm0 + e;
          int tt = gm & (TSEQ - 1), bb = gm >> 11;
          dst[(size_t)((bb * NHEAD + hh) * TSEQ + tt) * DHEAD + dd] = f2bf((acc[i][j][e] + bv) * sc);
        }
      }
    }
  }
}

// ---------- flash attention (LDS-staged K/V, double-buffered, swizzled) ----------
// Block bx handles q-tiles bx and NT-1-bx (balanced). All 4 waves share K/V tiles,
// staged once per block via global_load_lds (width 16), pre-swizzled global source
// (rule 21). K/V XOR: colbyte ^= (row&7)<<4.  P: wave-private [16][64] ushort,
// XOR-swizzled (ushort idx ^= (cc&7)<<3) — LDS total 40960 B = 4 blocks/CU.
// S^T = mfma(K,Q) (lane-local q-row softmax, defer-max THR=8); PV as O^T = mfma(V^T, P).
__global__ __launch_bounds__(256)
void attn_fwd(const ushort* __restrict__ qg, const ushort* __restrict__ kg,
              const ushort* __restrict__ vTg, ushort* __restrict__ ybb)
{
  // LDS: K[2] @ 0 (each 64 rows x 128B, swizzled), V[2] @ 16384, P @ 32768 (4 waves x 2048B)
  __shared__ __align__(16) char smem[40960];
  const int t = threadIdx.x, lane = t & 63, w = t >> 6;
  const int cc = lane & 15, gg = lane >> 4;
  const int NT = TSEQ / 64;
  const int bx = blockIdx.x, bh = blockIdx.y;
  const int b = bh / NHEAD, h = bh - b * NHEAD;

  const char* Kg = (const char*)(kg + (size_t)bh * TSEQ * DHEAD);   // [T][64] rows, 128B stride
  const char* Vg = (const char*)(vTg + (size_t)bh * TSEQ * DHEAD);  // [64][T] rows, 4096B stride

  // staging geometry: chunk c = w*2+i covers LDS bytes [c*1024, +1024) = rows c*8..c*8+7
  const int srow = lane >> 3;           // lane's sub-row in its 8-row chunk (= row&7)
  const int ssw  = ((lane & 7) * 16) ^ (srow << 4);  // pre-swizzled source colbyte

  ushort* Pw = (ushort*)(smem + 32768 + w * 2048);   // wave-private [16][64], swizzled
  const int sw8 = (cc & 7) << 3;                     // P swizzle in ushort units

  auto stage = [&](int pp, int kt) {
#pragma unroll
    for (int i = 0; i < 2; ++i) {
      const int c = w * 2 + i;
      const char* gk = Kg + (size_t)(kt * 64 + c * 8 + srow) * 128 + ssw;
      __builtin_amdgcn_global_load_lds(
          (const __attribute__((address_space(1))) unsigned*)gk,
          (__attribute__((address_space(3))) unsigned*)(smem + pp * 8192 + c * 1024),
          16, 0, 0);
      const char* gv = Vg + (size_t)(c * 8 + srow) * (TSEQ * 2) + (size_t)kt * 128 + ssw;
      __builtin_amdgcn_global_load_lds(
          (const __attribute__((address_space(1))) unsigned*)gv,
          (__attribute__((address_space(3))) unsigned*)(smem + 16384 + pp * 8192 + c * 1024),
          16, 0, 0);
    }
  };

  int p = 0;
  for (int pass = 0; pass < 2; ++pass) {
    const int qt = pass ? (NT - 1 - bx) : bx;
    const int qrow0 = qt * 64 + w * 16;

    const ushort* Qp = qg + ((size_t)bh * TSEQ + qrow0) * DHEAD;
    bf16x8 fq0 = *(const bf16x8*)(Qp + cc * DHEAD + 8 * gg);
    bf16x8 fq1 = *(const bf16x8*)(Qp + cc * DHEAD + 32 + 8 * gg);

    f32x4 o[4];   // O^T: o[dt][e] = O^T[d = dt*16 + gg*4 + e, q = cc]
#pragma unroll
    for (int i = 0; i < 4; ++i) o[i] = (f32x4){0.f, 0.f, 0.f, 0.f};
    float m = -1e30f, l = 0.f;

    stage(p, 0);
    asm volatile("s_waitcnt vmcnt(0)" ::: "memory");
    __syncthreads();

    for (int kt = 0; kt <= qt; ++kt) {
      if (kt < qt) stage(p ^ 1, kt + 1);   // prefetch next tile; lands by end-of-iter barrier

      const char* Kl = smem + p * 8192;
      const char* Vl = smem + 16384 + p * 8192;
      f32x4 st[4];   // st[ct][e] = S^T[key = 16ct + 4gg + e, q = cc]
#pragma unroll
      for (int ct = 0; ct < 4; ++ct) st[ct] = (f32x4){0.f, 0.f, 0.f, 0.f};
      __builtin_amdgcn_s_setprio(1);
#pragma unroll
      for (int ct = 0; ct < 4; ++ct) {
        const int r = ct * 16 + cc;
        const char* kb = Kl + r * 128;
        bf16x8 fk0 = *(const bf16x8*)(kb + ((gg * 16) ^ ((r & 7) << 4)));
        bf16x8 fk1 = *(const bf16x8*)(kb + ((64 + gg * 16) ^ ((r & 7) << 4)));
        st[ct] = __builtin_amdgcn_mfma_f32_16x16x32_bf16(fk0, fq0, st[ct], 0, 0, 0);
        st[ct] = __builtin_amdgcn_mfma_f32_16x16x32_bf16(fk1, fq1, st[ct], 0, 0, 0);
      }
      __builtin_amdgcn_s_setprio(0);

      if (kt == qt) {   // causal mask on diagonal tile (Q pre-scaled by 1/8)
#pragma unroll
        for (int ct = 0; ct < 4; ++ct)
#pragma unroll
          for (int e = 0; e < 4; ++e)
            if (ct * 16 + gg * 4 + e > w * 16 + cc) st[ct][e] = -1e30f;
      }
      float ml = st[0][0];
#pragma unroll
      for (int ct = 0; ct < 4; ++ct)
#pragma unroll
        for (int e = 0; e < 4; ++e) ml = fmaxf(ml, st[ct][e]);
      ml = fmaxf(ml, __shfl_xor(ml, 16, 64));
      ml = fmaxf(ml, __shfl_xor(ml, 32, 64));
      float mn = m;
      if (!__all(ml - m <= 8.f)) {   // defer-max (T13): rescale only when max grows
        mn = fmaxf(m, ml);
        float al = __expf(m - mn);
#pragma unroll
        for (int dt = 0; dt < 4; ++dt)
#pragma unroll
          for (int e = 0; e < 4; ++e) o[dt][e] *= al;
        l *= al;
        m = mn;
      }
      float ps = 0.f;
#pragma unroll
      for (int ct = 0; ct < 4; ++ct)
#pragma unroll
        for (int e = 0; e < 4; ++e) { float pp = __expf(st[ct][e] - mn); st[ct][e] = pp; ps += pp; }
#pragma unroll
      for (int ct = 0; ct < 4; ++ct) {
        uint2 pw;
        pw.x = cvt_pk_bf16(st[ct][0], st[ct][1]);
        pw.y = cvt_pk_bf16(st[ct][2], st[ct][3]);
        *(uint2*)&Pw[cc * 64 + ((ct * 16 + gg * 4) ^ sw8)] = pw;
      }
      ps += __shfl_xor(ps, 16, 64);
      ps += __shfl_xor(ps, 32, 64);
      l += ps;
      lds_fence();   // wave-local: P writes complete before fragment reads
      __builtin_amdgcn_s_setprio(1);
#pragma unroll
      for (int kc = 0; kc < 2; ++kc) {
        bf16x8 pb = *(const bf16x8*)&Pw[cc * 64 + ((kc * 32 + 8 * gg) ^ sw8)];
#pragma unroll
        for (int dt = 0; dt < 4; ++dt) {
          const int rd = dt * 16 + cc;
          bf16x8 fv = *(const bf16x8*)(Vl + rd * 128 + ((kc * 64 + gg * 16) ^ ((rd & 7) << 4)));
          o[dt] = __builtin_amdgcn_mfma_f32_16x16x32_bf16(fv, pb, o[dt], 0, 0, 0);
        }
      }
      __builtin_amdgcn_s_setprio(0);
      asm volatile("s_waitcnt vmcnt(0)" ::: "memory");   // next tile's stage landed
      __syncthreads();                                   // all waves done reading buf p
      p ^= 1;
    }

    float inv = 1.0f / l;
    ushort* yrow = ybb + (size_t)(b * TSEQ + qrow0 + cc) * CEMB + h * DHEAD;
#pragma unroll
    for (int dt = 0; dt < 4; ++dt) {
      uint2 pw;
      pw.x = cvt_pk_bf16(o[dt][0] * inv, o[dt][1] * inv);
      pw.y = cvt_pk_bf16(o[dt][2] * inv, o[dt][3] * inv);
      *(uint2*)(yrow + dt * 16 + gg * 4) = pw;
    }
  }
}

extern "C" void kernel_launch(void* const* d_in, const int* in_sizes, int n_in,
                              void* d_out, int out_size, void* d_ws, size_t ws_size,
                              hipStream_t stream)
{
  (void)in_sizes; (void)n_in; (void)out_size; (void)ws_size;
  const float* x  = (const float*)d_in[0];
  const float* Wa = (const float*)d_in[1];
  const float* ba = (const float*)d_in[2];
  const float* Wo = (const float*)d_in[3];
  const float* bo = (const float*)d_in[4];
  float* out = (float*)d_out;

  char* p = (char*)d_ws;
  ushort* WaT  = (ushort*)p; p += (size_t)3 * CEMB * CEMB * 2;               // [2304][768] bf16
  ushort* WoT  = (ushort*)p; p += (size_t)CEMB * CEMB * 2;                   // [768][768] bf16
  ushort* xb   = (ushort*)p; p += (size_t)NBATCH * TSEQ * CEMB * 2;          // x bf16 [B*T][C]
  ushort* qb   = (ushort*)p; p += (size_t)NBATCH * NHEAD * TSEQ * DHEAD * 2; // [B,H,T,D]
  ushort* kb   = (ushort*)p; p += (size_t)NBATCH * NHEAD * TSEQ * DHEAD * 2;
  ushort* vtmp = (ushort*)p; p += (size_t)NBATCH * NHEAD * TSEQ * DHEAD * 2;
  ushort* vT   = (ushort*)p; p += (size_t)NBATCH * NHEAD * TSEQ * DHEAD * 2; // [B,H,D,T]
  ushort* yb   = (ushort*)p; p += (size_t)NBATCH * TSEQ * CEMB * 2;          // attn out bf16 [B*T][C]

  dim3 tb(32, 8);
  cast_x<<<NBATCH * TSEQ * CEMB / (256 * 8), 256, 0, stream>>>(x, xb, NBATCH * TSEQ * CEMB);
  transpose_w<<<dim3(3 * CEMB / 32, CEMB / 32), tb, 0, stream>>>(Wa, WaT, CEMB, 3 * CEMB);
  transpose_w<<<dim3(CEMB / 32, CEMB / 32), tb, 0, stream>>>(Wo, WoT, CEMB, CEMB);
  gemm_bf16<1><<<dim3(3 * CEMB / 128, NBATCH * TSEQ / 128), 256, 0, stream>>>(
      xb, WaT, ba, nullptr, qb, kb, vtmp, NBATCH * TSEQ, 3 * CEMB, CEMB);
  transpose_v<<<dim3(TSEQ / 32, DHEAD / 32, NBATCH * NHEAD), tb, 0, stream>>>(vtmp, vT);
  attn_fwd<<<dim3(TSEQ / 128, NBATCH * NHEAD), 256, 0, stream>>>(qb, kb, vT, yb);
  gemm_bf16<0><<<dim3(CEMB / 128, NBATCH * TSEQ / 128), 256, 0, stream>>>(
      yb, WoT, bo, out, nullptr, nullptr, nullptr, NBATCH * TSEQ, CEMB, CEMB);
}

// Round 8
// 142.548 us; speedup vs baseline: 3.1662x; 1.0762x over previous
//
#include <hip/hip_runtime.h>
#include <hip/hip_bf16.h>

#define NHEAD 12
#define TSEQ 2048
#define CEMB 768
#define DHEAD 64
#define NBATCH 4

typedef __attribute__((ext_vector_type(8))) short bf16x8;
typedef __attribute__((ext_vector_type(4))) float f32x4;

__device__ __forceinline__ ushort f2bf(float f) {
  union { float f; unsigned u; } v; v.f = f;
  unsigned u = v.u;
  u += 0x7FFFu + ((u >> 16) & 1u);   // RNE to bf16
  return (ushort)(u >> 16);
}

// packed f32x2 -> bf16x2 (1 inst, RNE) — T12 primitive
__device__ __forceinline__ unsigned cvt_pk_bf16(float lo, float hi) {
  unsigned r;
  asm("v_cvt_pk_bf16_f32 %0, %1, %2" : "=v"(r) : "v"(lo), "v"(hi));
  return r;
}

// raw v_exp_f32: D = 2^S0 (scores are pre-scaled to log2 domain)
__device__ __forceinline__ float exp2_raw(float x) {
  float r;
  asm("v_exp_f32 %0, %1" : "=v"(r) : "v"(x));
  return r;
}

// wave-local LDS ordering (P buffer is wave-private; no block barrier needed)
__device__ __forceinline__ void lds_fence() {
  asm volatile("s_waitcnt lgkmcnt(0)" ::: "memory");
  __builtin_amdgcn_sched_barrier(0);   // rule 18: pin ops after the waitcnt
}

// ---------- fp32 -> bf16 bulk cast (x) ----------
__global__ __launch_bounds__(256)
void cast_x(const float* __restrict__ src, ushort* __restrict__ dst, int n) {
  int i = (blockIdx.x * 256 + threadIdx.x) * 8;
  if (i < n) {
    float4 v0 = *(const float4*)(src + i);
    float4 v1 = *(const float4*)(src + i + 4);
    bf16x8 w;
    w[0] = (short)f2bf(v0.x); w[1] = (short)f2bf(v0.y);
    w[2] = (short)f2bf(v0.z); w[3] = (short)f2bf(v0.w);
    w[4] = (short)f2bf(v1.x); w[5] = (short)f2bf(v1.y);
    w[6] = (short)f2bf(v1.z); w[7] = (short)f2bf(v1.w);
    *(bf16x8*)(dst + i) = w;
  }
}

// ---------- fp32 [R][C] -> bf16 [C][R] (weight pre-transpose) ----------
__global__ void transpose_w(const float* __restrict__ src, ushort* __restrict__ dst,
                            int R, int C) {
  __shared__ float tile[32][33];
  int c0 = blockIdx.x * 32, r0 = blockIdx.y * 32;
  int tx = threadIdx.x, ty = threadIdx.y;  // block (32,8)
#pragma unroll
  for (int j = 0; j < 4; ++j)
    tile[ty + j * 8][tx] = src[(size_t)(r0 + ty + j * 8) * C + c0 + tx];
  __syncthreads();
#pragma unroll
  for (int j = 0; j < 4; ++j)
    dst[(size_t)(c0 + ty + j * 8) * R + r0 + tx] = f2bf(tile[tx][ty + j * 8]);
}

// ---------- bf16 v [BH][T][D] -> vT [BH][D][T] ----------
__global__ void transpose_v(const ushort* __restrict__ src, ushort* __restrict__ dst) {
  __shared__ ushort tile[32][33];
  int bh = blockIdx.z;
  int t0 = blockIdx.x * 32, d0 = blockIdx.y * 32;
  int tx = threadIdx.x, ty = threadIdx.y;  // block (32,8)
  const ushort* s = src + (size_t)bh * TSEQ * DHEAD;
  ushort* o = dst + (size_t)bh * TSEQ * DHEAD;
#pragma unroll
  for (int j = 0; j < 4; ++j)
    tile[ty + j * 8][tx] = s[(t0 + ty + j * 8) * DHEAD + d0 + tx];
  __syncthreads();
#pragma unroll
  for (int j = 0; j < 4; ++j)
    o[(size_t)(d0 + ty + j * 8) * TSEQ + t0 + tx] = tile[tx][ty + j * 8];
}

// ---------- bf16 MFMA GEMM (m97 structure): C[M][N] = A(bf16,[M][K]) * BT(bf16,[N][K])^T + bias
// A and B tiles staged via global_load_lds width=16 (linear LDS dest), slot-XOR swizzle
// s ^= (row>>1)&3 pre-applied on the GLOBAL source + same XOR on the ds_read side (rule 21).
// EPI=0: fp32 out [M][N].  EPI=1: scatter qkv -> q/k/v bf16 [B,H,T,D],
//        q pre-scaled by 0.125*log2(e) (softmax runs in exp2 domain).
template<int EPI>
__global__ __launch_bounds__(256)
void gemm_bf16(const ushort* __restrict__ A, const ushort* __restrict__ BT,
               const float* __restrict__ bias, float* __restrict__ outF,
               ushort* __restrict__ qd, ushort* __restrict__ kd, ushort* __restrict__ vd,
               int M, int N, int K)
{
  __shared__ __align__(16) char smem[16384];   // As 8KB @0, Bs 8KB @8192
  const int t = threadIdx.x;
  const int lane = t & 63, wv = t >> 6;
  const int cc = lane & 15, gg = lane >> 4;
  const int m0 = blockIdx.y * 128, n0 = blockIdx.x * 128;
  const int wm = (wv >> 1) * 64, wn = (wv & 1) * 64;

  // staging: thread covers LDS linear offsets o0 = wv*1024 + lane*16 and o0 + 4096.
  // LDS(row, slot) holds G(row, slot ^ ((row>>1)&3));  row = o>>6 (64B rows), slot = (o>>4)&3
  const int o0 = wv * 1024 + lane * 16;
  const int o1 = o0 + 4096;
  const int r0s = o0 >> 6, s0s = (o0 >> 4) & 3;
  const int r1s = o1 >> 6, s1s = (o1 >> 4) & 3;
  const size_t Kb = (size_t)K * 2;
  const char* a0p = (const char*)A  + (size_t)(m0 + r0s) * Kb + ((s0s ^ ((r0s >> 1) & 3)) << 4);
  const char* a1p = (const char*)A  + (size_t)(m0 + r1s) * Kb + ((s1s ^ ((r1s >> 1) & 3)) << 4);
  const char* b0p = (const char*)BT + (size_t)(n0 + r0s) * Kb + ((s0s ^ ((r0s >> 1) & 3)) << 4);
  const char* b1p = (const char*)BT + (size_t)(n0 + r1s) * Kb + ((s1s ^ ((r1s >> 1) & 3)) << 4);

  char* As = smem;
  char* Bs = smem + 8192;

  f32x4 acc[4][4];
#pragma unroll
  for (int i = 0; i < 4; ++i)
#pragma unroll
    for (int j = 0; j < 4; ++j) acc[i][j] = (f32x4){0.f, 0.f, 0.f, 0.f};

  const int KB = K * 2;   // row bytes
  for (int kb = 0; kb < KB; kb += 64) {
    __builtin_amdgcn_global_load_lds(
        (const __attribute__((address_space(1))) unsigned*)(a0p + kb),
        (__attribute__((address_space(3))) unsigned*)(As + wv * 1024), 16, 0, 0);
    __builtin_amdgcn_global_load_lds(
        (const __attribute__((address_space(1))) unsigned*)(a1p + kb),
        (__attribute__((address_space(3))) unsigned*)(As + wv * 1024 + 4096), 16, 0, 0);
    __builtin_amdgcn_global_load_lds(
        (const __attribute__((address_space(1))) unsigned*)(b0p + kb),
        (__attribute__((address_space(3))) unsigned*)(Bs + wv * 1024), 16, 0, 0);
    __builtin_amdgcn_global_load_lds(
        (const __attribute__((address_space(1))) unsigned*)(b1p + kb),
        (__attribute__((address_space(3))) unsigned*)(Bs + wv * 1024 + 4096), 16, 0, 0);
    __syncthreads();   // drains vmcnt(0): staged tile visible to all waves
    bf16x8 fa[4], fb[4];
#pragma unroll
    for (int i = 0; i < 4; ++i) {
      const int r = wm + i * 16 + cc;
      fa[i] = *(const bf16x8*)(As + r * 64 + ((gg ^ ((r >> 1) & 3)) << 4));
    }
#pragma unroll
    for (int j = 0; j < 4; ++j) {
      const int r = wn + j * 16 + cc;
      fb[j] = *(const bf16x8*)(Bs + r * 64 + ((gg ^ ((r >> 1) & 3)) << 4));
    }
    __builtin_amdgcn_s_setprio(1);
#pragma unroll
    for (int i = 0; i < 4; ++i)
#pragma unroll
      for (int j = 0; j < 4; ++j)
        acc[i][j] = __builtin_amdgcn_mfma_f32_16x16x32_bf16(fa[i], fb[j], acc[i][j], 0, 0, 0);
    __builtin_amdgcn_s_setprio(0);
    __syncthreads();   // all reads done before next stage overwrites
  }

#pragma unroll
  for (int i = 0; i < 4; ++i) {
#pragma unroll
    for (int j = 0; j < 4; ++j) {
      int gm0 = m0 + wm + i * 16 + gg * 4;
      int gn  = n0 + wn + j * 16 + cc;
      float bv = bias[gn];
      if (EPI == 0) {
#pragma unroll
        for (int e = 0; e < 4; ++e)
          outF[(size_t)(gm0 + e) * N + gn] = acc[i][j][e] + bv;
      } else {
        int which = gn / CEMB;
        int r = gn - which * CEMB;
        int hh = r >> 6, dd = r & 63;
        ushort* dst = which == 0 ? qd : (which == 1 ? kd : vd);
        // q scale: 1/sqrt(D) * log2(e) — softmax computed with exp2
        float sc = (which == 0) ? 0.125f * 1.4426950408889634f : 1.0f;
#pragma unroll
        for (int e = 0; e < 4; ++e) {
          int gm = gm0 + e;
          int tt = gm & (TSEQ - 1), bb = gm >> 11;
          dst[(size_t)((bb * NHEAD + hh) * TSEQ + tt) * DHEAD + dd] = f2bf((acc[i][j][e] + bv) * sc);
        }
      }
    }
  }
}

// ---------- flash attention (LDS-staged K/V, double-buffered, swizzled, XCD-grouped) ----------
// 1-D grid of 768 blocks; decode maps all 16 bx-blocks of one head onto ONE XCD
// (T1: K/V becomes XCD-L2-resident; HBM re-fetch across bx-blocks eliminated).
// Block bx handles q-tiles bx and NT-1-bx (balanced, NT+1 key-tiles/wave).
// K/V staged per block via global_load_lds (rule 21 pre-swizzled source, XOR (row&7)<<4).
// P: wave-private [16][64] ushort, XOR-swizzled — LDS 40960 B.
// Softmax in exp2 domain (Q pre-scaled by log2e/8), defer-max THR = 8*log2e.
__global__ __launch_bounds__(256)
void attn_fwd(const ushort* __restrict__ qg, const ushort* __restrict__ kg,
              const ushort* __restrict__ vTg, ushort* __restrict__ ybb)
{
  // LDS: K[2] @ 0 (each 64 rows x 128B, swizzled), V[2] @ 16384, P @ 32768 (4 waves x 2048B)
  __shared__ __align__(16) char smem[40960];
  const int t = threadIdx.x, lane = t & 63, w = t >> 6;
  const int cc = lane & 15, gg = lane >> 4;
  const int NT = TSEQ / 64;
  // XCD-grouped decode: L%8 = XCD slot; same bh -> same XCD (48 bh = 8 XCD x 6)
  const int L = blockIdx.x;
  const int r9 = L >> 3;
  const int bx = r9 & 15;
  const int bh = (L & 7) + 8 * (r9 >> 4);
  const int b = bh / NHEAD, h = bh - b * NHEAD;

  const char* Kg = (const char*)(kg + (size_t)bh * TSEQ * DHEAD);   // [T][64] rows, 128B stride
  const char* Vg = (const char*)(vTg + (size_t)bh * TSEQ * DHEAD);  // [64][T] rows, 4096B stride

  // staging geometry: chunk c = w*2+i covers LDS bytes [c*1024, +1024) = rows c*8..c*8+7
  const int srow = lane >> 3;           // lane's sub-row in its 8-row chunk (= row&7)
  const int ssw  = ((lane & 7) * 16) ^ (srow << 4);  // pre-swizzled source colbyte

  ushort* Pw = (ushort*)(smem + 32768 + w * 2048);   // wave-private [16][64], swizzled
  const int sw8 = (cc & 7) << 3;                     // P swizzle in ushort units

  auto stage = [&](int pp, int kt) {
#pragma unroll
    for (int i = 0; i < 2; ++i) {
      const int c = w * 2 + i;
      const char* gk = Kg + (size_t)(kt * 64 + c * 8 + srow) * 128 + ssw;
      __builtin_amdgcn_global_load_lds(
          (const __attribute__((address_space(1))) unsigned*)gk,
          (__attribute__((address_space(3))) unsigned*)(smem + pp * 8192 + c * 1024),
          16, 0, 0);
      const char* gv = Vg + (size_t)(c * 8 + srow) * (TSEQ * 2) + (size_t)kt * 128 + ssw;
      __builtin_amdgcn_global_load_lds(
          (const __attribute__((address_space(1))) unsigned*)gv,
          (__attribute__((address_space(3))) unsigned*)(smem + 16384 + pp * 8192 + c * 1024),
          16, 0, 0);
    }
  };

  int p = 0;
  for (int pass = 0; pass < 2; ++pass) {
    const int qt = pass ? (NT - 1 - bx) : bx;
    const int qrow0 = qt * 64 + w * 16;

    const ushort* Qp = qg + ((size_t)bh * TSEQ + qrow0) * DHEAD;
    bf16x8 fq0 = *(const bf16x8*)(Qp + cc * DHEAD + 8 * gg);
    bf16x8 fq1 = *(const bf16x8*)(Qp + cc * DHEAD + 32 + 8 * gg);

    f32x4 o[4];   // O^T: o[dt][e] = O^T[d = dt*16 + gg*4 + e, q = cc]
#pragma unroll
    for (int i = 0; i < 4; ++i) o[i] = (f32x4){0.f, 0.f, 0.f, 0.f};
    float m = -1e30f, l = 0.f;

    stage(p, 0);
    asm volatile("s_waitcnt vmcnt(0)" ::: "memory");
    __syncthreads();

    for (int kt = 0; kt <= qt; ++kt) {
      if (kt < qt) stage(p ^ 1, kt + 1);   // prefetch next tile; lands by end-of-iter barrier

      const char* Kl = smem + p * 8192;
      const char* Vl = smem + 16384 + p * 8192;
      f32x4 st[4];   // st[ct][e] = S^T[key = 16ct + 4gg + e, q = cc]  (log2 domain)
#pragma unroll
      for (int ct = 0; ct < 4; ++ct) st[ct] = (f32x4){0.f, 0.f, 0.f, 0.f};
      __builtin_amdgcn_s_setprio(1);
#pragma unroll
      for (int ct = 0; ct < 4; ++ct) {
        const int r = ct * 16 + cc;
        const char* kb = Kl + r * 128;
        bf16x8 fk0 = *(const bf16x8*)(kb + ((gg * 16) ^ ((r & 7) << 4)));
        bf16x8 fk1 = *(const bf16x8*)(kb + ((64 + gg * 16) ^ ((r & 7) << 4)));
        st[ct] = __builtin_amdgcn_mfma_f32_16x16x32_bf16(fk0, fq0, st[ct], 0, 0, 0);
        st[ct] = __builtin_amdgcn_mfma_f32_16x16x32_bf16(fk1, fq1, st[ct], 0, 0, 0);
      }
      __builtin_amdgcn_s_setprio(0);

      if (kt == qt) {   // causal mask on diagonal tile
#pragma unroll
        for (int ct = 0; ct < 4; ++ct)
#pragma unroll
          for (int e = 0; e < 4; ++e)
            if (ct * 16 + gg * 4 + e > w * 16 + cc) st[ct][e] = -1e30f;
      }
      float ml = st[0][0];
#pragma unroll
      for (int ct = 0; ct < 4; ++ct)
#pragma unroll
        for (int e = 0; e < 4; ++e) ml = fmaxf(ml, st[ct][e]);
      ml = fmaxf(ml, __shfl_xor(ml, 16, 64));
      ml = fmaxf(ml, __shfl_xor(ml, 32, 64));
      float mn = m;
      if (!__all(ml - m <= 11.54f)) {   // defer-max (T13), THR = 8*log2e
        mn = fmaxf(m, ml);
        float al = exp2_raw(m - mn);
#pragma unroll
        for (int dt = 0; dt < 4; ++dt)
#pragma unroll
          for (int e = 0; e < 4; ++e) o[dt][e] *= al;
        l *= al;
        m = mn;
      }
      float ps = 0.f;
#pragma unroll
      for (int ct = 0; ct < 4; ++ct)
#pragma unroll
        for (int e = 0; e < 4; ++e) { float pp = exp2_raw(st[ct][e] - mn); st[ct][e] = pp; ps += pp; }
#pragma unroll
      for (int ct = 0; ct < 4; ++ct) {
        uint2 pw;
        pw.x = cvt_pk_bf16(st[ct][0], st[ct][1]);
        pw.y = cvt_pk_bf16(st[ct][2], st[ct][3]);
        *(uint2*)&Pw[cc * 64 + ((ct * 16 + gg * 4) ^ sw8)] = pw;
      }
      ps += __shfl_xor(ps, 16, 64);
      ps += __shfl_xor(ps, 32, 64);
      l += ps;
      lds_fence();   // wave-local: P writes complete before fragment reads
      __builtin_amdgcn_s_setprio(1);
#pragma unroll
      for (int kc = 0; kc < 2; ++kc) {
        bf16x8 pb = *(const bf16x8*)&Pw[cc * 64 + ((kc * 32 + 8 * gg) ^ sw8)];
#pragma unroll
        for (int dt = 0; dt < 4; ++dt) {
          const int rd = dt * 16 + cc;
          bf16x8 fv = *(const bf16x8*)(Vl + rd * 128 + ((kc * 64 + gg * 16) ^ ((rd & 7) << 4)));
          o[dt] = __builtin_amdgcn_mfma_f32_16x16x32_bf16(fv, pb, o[dt], 0, 0, 0);
        }
      }
      __builtin_amdgcn_s_setprio(0);
      asm volatile("s_waitcnt vmcnt(0)" ::: "memory");   // next tile's stage landed
      __syncthreads();                                   // all waves done reading buf p
      p ^= 1;
    }

    float inv = 1.0f / l;
    ushort* yrow = ybb + (size_t)(b * TSEQ + qrow0 + cc) * CEMB + h * DHEAD;
#pragma unroll
    for (int dt = 0; dt < 4; ++dt) {
      uint2 pw;
      pw.x = cvt_pk_bf16(o[dt][0] * inv, o[dt][1] * inv);
      pw.y = cvt_pk_bf16(o[dt][2] * inv, o[dt][3] * inv);
      *(uint2*)(yrow + dt * 16 + gg * 4) = pw;
    }
  }
}

extern "C" void kernel_launch(void* const* d_in, const int* in_sizes, int n_in,
                              void* d_out, int out_size, void* d_ws, size_t ws_size,
                              hipStream_t stream)
{
  (void)in_sizes; (void)n_in; (void)out_size; (void)ws_size;
  const float* x  = (const float*)d_in[0];
  const float* Wa = (const float*)d_in[1];
  const float* ba = (const float*)d_in[2];
  const float* Wo = (const float*)d_in[3];
  const float* bo = (const float*)d_in[4];
  float* out = (float*)d_out;

  char* p = (char*)d_ws;
  ushort* WaT  = (ushort*)p; p += (size_t)3 * CEMB * CEMB * 2;               // [2304][768] bf16
  ushort* WoT  = (ushort*)p; p += (size_t)CEMB * CEMB * 2;                   // [768][768] bf16
  ushort* xb   = (ushort*)p; p += (size_t)NBATCH * TSEQ * CEMB * 2;          // x bf16 [B*T][C]
  ushort* qb   = (ushort*)p; p += (size_t)NBATCH * NHEAD * TSEQ * DHEAD * 2; // [B,H,T,D]
  ushort* kb   = (ushort*)p; p += (size_t)NBATCH * NHEAD * TSEQ * DHEAD * 2;
  ushort* vtmp = (ushort*)p; p += (size_t)NBATCH * NHEAD * TSEQ * DHEAD * 2;
  ushort* vT   = (ushort*)p; p += (size_t)NBATCH * NHEAD * TSEQ * DHEAD * 2; // [B,H,D,T]
  ushort* yb   = (ushort*)p; p += (size_t)NBATCH * TSEQ * CEMB * 2;          // attn out bf16 [B*T][C]

  dim3 tb(32, 8);
  cast_x<<<NBATCH * TSEQ * CEMB / (256 * 8), 256, 0, stream>>>(x, xb, NBATCH * TSEQ * CEMB);
  transpose_w<<<dim3(3 * CEMB / 32, CEMB / 32), tb, 0, stream>>>(Wa, WaT, CEMB, 3 * CEMB);
  transpose_w<<<dim3(CEMB / 32, CEMB / 32), tb, 0, stream>>>(Wo, WoT, CEMB, CEMB);
  gemm_bf16<1><<<dim3(3 * CEMB / 128, NBATCH * TSEQ / 128), 256, 0, stream>>>(
      xb, WaT, ba, nullptr, qb, kb, vtmp, NBATCH * TSEQ, 3 * CEMB, CEMB);
  transpose_v<<<dim3(TSEQ / 32, DHEAD / 32, NBATCH * NHEAD), tb, 0, stream>>>(vtmp, vT);
  attn_fwd<<<dim3((TSEQ / 128) * NBATCH * NHEAD), 256, 0, stream>>>(qb, kb, vT, yb);
  gemm_bf16<0><<<dim3(CEMB / 128, NBATCH * TSEQ / 128), 256, 0, stream>>>(
      yb, WoT, bo, out, nullptr, nullptr, nullptr, NBATCH * TSEQ, CEMB, CEMB);
}